// Round 10
// baseline (14986.618 us; speedup 1.0000x reference)
//
#include <hip/hip_runtime.h>
#include <cstdint>

#define NF 128   // node feature / hidden width
#define G4 512   // 4*H gates

typedef float v2f __attribute__((ext_vector_type(2)));

__device__ __forceinline__ float frcp(float x) { return __builtin_amdgcn_rcpf(x); }
__device__ __forceinline__ float ftanh(float x) {
  float e = __expf(2.f * x);
  return 1.f - 2.f * frcp(e + 1.f);
}

// DPP quad-perm lane exchanges (VALU, no LDS pipe, no barrier)
__device__ __forceinline__ float dpp_xor1(float x) {  // lane ^ 1 within quad
  int r = __builtin_amdgcn_update_dpp(0, __float_as_int(x), 0xB1, 0xF, 0xF, true);
  return __int_as_float(r);
}
__device__ __forceinline__ float dpp_xor2(float x) {  // lane ^ 2 within quad
  int r = __builtin_amdgcn_update_dpp(0, __float_as_int(x), 0x4E, 0xF, 0xF, true);
  return __int_as_float(r);
}
__device__ __forceinline__ float swz_xor4(float x) {  // lane ^ 4 (LDS swizzle)
  return __int_as_float(__builtin_amdgcn_ds_swizzle(__float_as_int(x), 0x101F));
}

// ---------------- small utility kernels ----------------

__global__ void k_fill(float* p, float v, int n) {
  int i = blockIdx.x * blockDim.x + threadIdx.x;
  if (i < n) p[i] = v;
}

__global__ void k_detect_i64(const int* e, int npairs, int* flag) {
  int f = 1;
  for (int i = 1; i < 2 * npairs; i += 2)
    if (e[i] != 0) { f = 0; break; }
  *flag = f;
}

__device__ __forceinline__ int eidx(const void* edges, int i64, size_t pos) {
  if (i64) return (int)((const long long*)edges)[pos];
  return ((const int*)edges)[pos];
}

__global__ void k_count(const void* __restrict__ edges, const int* __restrict__ flag,
                        float* __restrict__ deg, int E) {
  int e = blockIdx.x * blockDim.x + threadIdx.x;
  if (e < E) {
    int d = eidx(edges, *flag, (size_t)E + e);
    unsafeAtomicAdd(&deg[d], 1.0f);
  }
}

__global__ void k_rsqrt(float* p, int n) {
  int i = blockIdx.x * blockDim.x + threadIdx.x;
  if (i < n) p[i] = rsqrtf(p[i]);
}

__global__ void k_t128(const float* __restrict__ in, float* __restrict__ out) {
  int n = blockIdx.x, k = threadIdx.x;
  out[n * 128 + k] = in[k * 128 + n];
}

__global__ void k_add(const float* a, const float* b, float* o, int n) {
  int i = blockIdx.x * blockDim.x + threadIdx.x;
  if (i < n) o[i] = a[i] + b[i];
}

// Weight prep for the 8-lane-group LSTM layout.
// Lane t: j = t&7, group g8 = t>>3 owns units {2g8, 2g8+1}.
// Chain m (m=0..7) of lane t computes the partial of ROW (j^m) of the group
// (row rr: gate = rr&3, du = rr>>2, W-row = gate*128 + 2g8+du) over columns
// [16j, 16j+16). XOR assignment makes the butterfly reduce select-free.
__global__ void k_wprep(const float* __restrict__ W, float* __restrict__ wp) {
  int t = blockIdx.x;        // 0..511
  int m = threadIdx.x;       // 0..127
  int j = t & 7;
  int g8 = t >> 3;
  int blk = m >> 4;          // chain index 0..7
  int k = m & 15;
  int rr = j ^ blk;          // row within group
  int gate = rr & 3, du = rr >> 2;
  int unit = 2 * g8 + du;
  int col = 16 * j + k;
  wp[(size_t)t * 128 + m] = W[(size_t)(gate * 128 + unit) * 128 + col];
}

// ---------------- GEMM: C[M,N] = A[M,K] @ B[N,K]^T (+bias) ----------------
__global__ __launch_bounds__(256)
void gemm_bt(const float* __restrict__ A, const float* __restrict__ B,
             const float* __restrict__ bias, float* __restrict__ C,
             int M, int N, int K) {
  __shared__ float As[32][68];
  __shared__ float Bs[32][68];
  const int bm = blockIdx.x * 64;
  const int bn = blockIdx.y * 64;
  const int tid = threadIdx.x;
  const int tm = (tid & 15) << 2;
  const int tn = (tid >> 4) << 2;
  float acc[4][4] = {};

  for (int k0 = 0; k0 < K; k0 += 32) {
#pragma unroll
    for (int l = 0; l < 2; ++l) {
      int idx = tid + l * 256;
      int row = idx >> 3;
      int k4 = (idx & 7) << 2;
      int ar = bm + row; ar = ar < M ? ar : M - 1;
      float4 av = *(const float4*)(A + (size_t)ar * K + k0 + k4);
      As[k4 + 0][row] = av.x; As[k4 + 1][row] = av.y;
      As[k4 + 2][row] = av.z; As[k4 + 3][row] = av.w;
      int br = bn + row; br = br < N ? br : N - 1;
      float4 bv = *(const float4*)(B + (size_t)br * K + k0 + k4);
      Bs[k4 + 0][row] = bv.x; Bs[k4 + 1][row] = bv.y;
      Bs[k4 + 2][row] = bv.z; Bs[k4 + 3][row] = bv.w;
    }
    __syncthreads();
#pragma unroll
    for (int kk = 0; kk < 32; ++kk) {
      float4 a = *(const float4*)&As[kk][tm];
      float4 b = *(const float4*)&Bs[kk][tn];
      float av[4] = {a.x, a.y, a.z, a.w};
      float bv[4] = {b.x, b.y, b.z, b.w};
#pragma unroll
      for (int i = 0; i < 4; ++i)
#pragma unroll
        for (int jj = 0; jj < 4; ++jj)
          acc[i][jj] = __builtin_fmaf(av[i], bv[jj], acc[i][jj]);
    }
    __syncthreads();
  }

  float4 bv4;
  if (bias) bv4 = *(const float4*)(bias + bn + tn);
  else bv4 = make_float4(0.f, 0.f, 0.f, 0.f);
#pragma unroll
  for (int i = 0; i < 4; ++i) {
    int row = bm + tm + i;
    if (row < M) {
      float4 v;
      v.x = acc[i][0] + bv4.x;
      v.y = acc[i][1] + bv4.y;
      v.z = acc[i][2] + bv4.z;
      v.w = acc[i][3] + bv4.w;
      *(float4*)(C + (size_t)row * N + bn + tn) = v;
    }
  }
}

// ---------------- GCN edge aggregation (atomic scatter) ----------------
__global__ __launch_bounds__(256)
void k_aggregate(const float* __restrict__ xw, const void* __restrict__ edges,
                 const int* __restrict__ flag, const float* __restrict__ dinv,
                 float* __restrict__ out, int E) {
  int e = blockIdx.x * 8 + (threadIdx.x >> 5);
  if (e >= E) return;
  int i64 = *flag;
  int s = eidx(edges, i64, e);
  int d = eidx(edges, i64, (size_t)E + e);
  float nrm = dinv[s] * dinv[d];
  int f4 = threadIdx.x & 31;
  float4 v = ((const float4*)xw)[(size_t)s * 32 + f4];
  float* op = out + (size_t)d * 128 + f4 * 4;
  unsafeAtomicAdd(op + 0, v.x * nrm);
  unsafeAtomicAdd(op + 1, v.y * nrm);
  unsafeAtomicAdd(op + 2, v.z * nrm);
  unsafeAtomicAdd(op + 3, v.w * nrm);
}

__global__ void k_finish(float* __restrict__ h, const float* __restrict__ xw,
                         const float* __restrict__ dinv, const float* __restrict__ b,
                         int N) {
  int i4 = blockIdx.x * blockDim.x + threadIdx.x;
  if (i4 >= N * 32) return;
  int n = i4 >> 5;
  int f4 = (i4 & 31) << 2;
  float di = dinv[n];
  float s = di * di;
  float4 ag = ((const float4*)h)[i4];
  float4 xv = ((const float4*)xw)[i4];
  float4 bv = *(const float4*)(b + f4);
  float4 r;
  r.x = fmaxf(__builtin_fmaf(xv.x, s, ag.x) + bv.x, 0.f);
  r.y = fmaxf(__builtin_fmaf(xv.y, s, ag.y) + bv.y, 0.f);
  r.z = fmaxf(__builtin_fmaf(xv.z, s, ag.z) + bv.z, 0.f);
  r.w = fmaxf(__builtin_fmaf(xv.w, s, ag.w) + bv.w, 0.f);
  ((float4*)h)[i4] = r;
}

// ---------------- sequential LSTM scan ----------------
// R9 post-mortem: the in-loop asm's "memory" clobber marked it mayLoad/
// mayStore, so the backend drained s_waitcnt vmcnt(0) BEFORE it every step --
// serializing the g_in load's HBM/L3 latency (~400-900 cyc, g_in=41MB streams
// past L2) into every one of the 20000 steps. That fixed ~600 cyc is why
// R7/R8/R9 all plateaued at ~1300-1400 cyc/step regardless of LDS/VALU edits.
// R10: (1) remove the "memory" clobber (asm's internal counted lgkmcnt is
// self-ordering; cross-iteration LDS ordering comes from __syncthreads which
// drains lgkm + fences); (2) distance-2 g_in prefetch pipeline so each load
// has ~2 full steps in flight.
__global__ __launch_bounds__(512)
__attribute__((amdgpu_waves_per_eu(2, 2)))
void k_lstm(const float* __restrict__ g_in, const float* __restrict__ wp,
            float* __restrict__ hs, int T) {
  const int t = threadIdx.x;
  const int j = t & 7;         // lane within 8-group (column slice)
  const int g8 = t >> 3;       // group: owns units 2g8, 2g8+1
  const int pos = t & 3;       // gate slot after reduce: 0=i 1=f 2=g 3=o
  const int du = (t >> 2) & 1;
  const int unit = 2 * g8 + du;
  const int row = pos * 128 + unit;   // g_in row this lane finishes with

  // h vector: col c stored at float index 20*(c>>4) + (c&15) (skew +4/chunk)
  __shared__ __align__(16) float hbuf[2][160];
  __shared__ float lds_cap[20736];               // 82944 B occupancy anchor

  if (t == 0) {
    volatile float* vp = lds_cap;
    vp[0] = 0.f;
  }

  // -------- one-time weight preload into physical v128..v255 --------
  {
    const float* wr = wp + (size_t)t * 128;
    asm volatile(
      "global_load_dwordx4 v[128:131], %0, off\n\t"
      "global_load_dwordx4 v[132:135], %0, off offset:16\n\t"
      "global_load_dwordx4 v[136:139], %0, off offset:32\n\t"
      "global_load_dwordx4 v[140:143], %0, off offset:48\n\t"
      "global_load_dwordx4 v[144:147], %0, off offset:64\n\t"
      "global_load_dwordx4 v[148:151], %0, off offset:80\n\t"
      "global_load_dwordx4 v[152:155], %0, off offset:96\n\t"
      "global_load_dwordx4 v[156:159], %0, off offset:112\n\t"
      "global_load_dwordx4 v[160:163], %0, off offset:128\n\t"
      "global_load_dwordx4 v[164:167], %0, off offset:144\n\t"
      "global_load_dwordx4 v[168:171], %0, off offset:160\n\t"
      "global_load_dwordx4 v[172:175], %0, off offset:176\n\t"
      "global_load_dwordx4 v[176:179], %0, off offset:192\n\t"
      "global_load_dwordx4 v[180:183], %0, off offset:208\n\t"
      "global_load_dwordx4 v[184:187], %0, off offset:224\n\t"
      "global_load_dwordx4 v[188:191], %0, off offset:240\n\t"
      "global_load_dwordx4 v[192:195], %0, off offset:256\n\t"
      "global_load_dwordx4 v[196:199], %0, off offset:272\n\t"
      "global_load_dwordx4 v[200:203], %0, off offset:288\n\t"
      "global_load_dwordx4 v[204:207], %0, off offset:304\n\t"
      "global_load_dwordx4 v[208:211], %0, off offset:320\n\t"
      "global_load_dwordx4 v[212:215], %0, off offset:336\n\t"
      "global_load_dwordx4 v[216:219], %0, off offset:352\n\t"
      "global_load_dwordx4 v[220:223], %0, off offset:368\n\t"
      "global_load_dwordx4 v[224:227], %0, off offset:384\n\t"
      "global_load_dwordx4 v[228:231], %0, off offset:400\n\t"
      "global_load_dwordx4 v[232:235], %0, off offset:416\n\t"
      "global_load_dwordx4 v[236:239], %0, off offset:432\n\t"
      "global_load_dwordx4 v[240:243], %0, off offset:448\n\t"
      "global_load_dwordx4 v[244:247], %0, off offset:464\n\t"
      "global_load_dwordx4 v[248:251], %0, off offset:480\n\t"
      "global_load_dwordx4 v[252:255], %0, off offset:496\n\t"
      "s_waitcnt vmcnt(0)"
      :: "v"(wr)
      : "v128","v129","v130","v131","v132","v133","v134","v135",
        "v136","v137","v138","v139","v140","v141","v142","v143",
        "v144","v145","v146","v147","v148","v149","v150","v151",
        "v152","v153","v154","v155","v156","v157","v158","v159",
        "v160","v161","v162","v163","v164","v165","v166","v167",
        "v168","v169","v170","v171","v172","v173","v174","v175",
        "v176","v177","v178","v179","v180","v181","v182","v183",
        "v184","v185","v186","v187","v188","v189","v190","v191",
        "v192","v193","v194","v195","v196","v197","v198","v199",
        "v200","v201","v202","v203","v204","v205","v206","v207",
        "v208","v209","v210","v211","v212","v213","v214","v215",
        "v216","v217","v218","v219","v220","v221","v222","v223",
        "v224","v225","v226","v227","v228","v229","v230","v231",
        "v232","v233","v234","v235","v236","v237","v238","v239",
        "v240","v241","v242","v243","v244","v245","v246","v247",
        "v248","v249","v250","v251","v252","v253","v254","v255");
  }

  if (t < 160) { hbuf[0][t] = 0.f; hbuf[1][t] = 0.f; }
  float c = 0.f;
  // distance-2 g_in prefetch pipeline
  float gn1 = g_in[row];                       // for step 0
  float gn2 = (T > 1) ? g_in[(size_t)G4 + row] : gn1;   // for step 1

  // 32-bit LDS byte addresses of this lane's chunk (validated in R8)
  const uint32_t adr0 = (uint32_t)(uintptr_t)&hbuf[0][20 * j];
  const uint32_t adr1 = (uint32_t)(uintptr_t)&hbuf[1][20 * j];

  __syncthreads();

  int pb = 0;
  const bool isg = (pos == 2);
  const bool sw1 = (pos & 1);
  const bool sw2 = (pos & 2) != 0;

  for (int step = 0; step < T; ++step) {
    float gcur = gn1;
    gn1 = gn2;
    int tn2 = step + 2 < T ? step + 2 : T - 1;
    gn2 = g_in[(size_t)tn2 * G4 + row];        // in flight ~2 steps

    uint32_t adr = pb ? adr1 : adr0;
    v2f a0, a1, a2, a3, a4, a5, a6, a7;
    // 4x ds_read_b128 (16 h floats) with counted waits; 8 chains x 8 pk-FMA
    // on named weight regs. NO memory clobber: internal lgkmcnt is exact
    // (barrier drained lgkm; no lgkm ops issue between barrier and here).
    asm volatile(
      "ds_read_b128 v[96:99], %8\n\t"
      "ds_read_b128 v[100:103], %8 offset:16\n\t"
      "ds_read_b128 v[104:107], %8 offset:32\n\t"
      "ds_read_b128 v[108:111], %8 offset:48\n\t"
      "s_waitcnt lgkmcnt(3)\n\t"
      "v_pk_mul_f32 %0, v[128:129], v[96:97]\n\t"
      "v_pk_mul_f32 %1, v[144:145], v[96:97]\n\t"
      "v_pk_mul_f32 %2, v[160:161], v[96:97]\n\t"
      "v_pk_mul_f32 %3, v[176:177], v[96:97]\n\t"
      "v_pk_mul_f32 %4, v[192:193], v[96:97]\n\t"
      "v_pk_mul_f32 %5, v[208:209], v[96:97]\n\t"
      "v_pk_mul_f32 %6, v[224:225], v[96:97]\n\t"
      "v_pk_mul_f32 %7, v[240:241], v[96:97]\n\t"
      "v_pk_fma_f32 %0, v[130:131], v[98:99], %0\n\t"
      "v_pk_fma_f32 %1, v[146:147], v[98:99], %1\n\t"
      "v_pk_fma_f32 %2, v[162:163], v[98:99], %2\n\t"
      "v_pk_fma_f32 %3, v[178:179], v[98:99], %3\n\t"
      "v_pk_fma_f32 %4, v[194:195], v[98:99], %4\n\t"
      "v_pk_fma_f32 %5, v[210:211], v[98:99], %5\n\t"
      "v_pk_fma_f32 %6, v[226:227], v[98:99], %6\n\t"
      "v_pk_fma_f32 %7, v[242:243], v[98:99], %7\n\t"
      "s_waitcnt lgkmcnt(2)\n\t"
      "v_pk_fma_f32 %0, v[132:133], v[100:101], %0\n\t"
      "v_pk_fma_f32 %1, v[148:149], v[100:101], %1\n\t"
      "v_pk_fma_f32 %2, v[164:165], v[100:101], %2\n\t"
      "v_pk_fma_f32 %3, v[180:181], v[100:101], %3\n\t"
      "v_pk_fma_f32 %4, v[196:197], v[100:101], %4\n\t"
      "v_pk_fma_f32 %5, v[212:213], v[100:101], %5\n\t"
      "v_pk_fma_f32 %6, v[228:229], v[100:101], %6\n\t"
      "v_pk_fma_f32 %7, v[244:245], v[100:101], %7\n\t"
      "v_pk_fma_f32 %0, v[134:135], v[102:103], %0\n\t"
      "v_pk_fma_f32 %1, v[150:151], v[102:103], %1\n\t"
      "v_pk_fma_f32 %2, v[166:167], v[102:103], %2\n\t"
      "v_pk_fma_f32 %3, v[182:183], v[102:103], %3\n\t"
      "v_pk_fma_f32 %4, v[198:199], v[102:103], %4\n\t"
      "v_pk_fma_f32 %5, v[214:215], v[102:103], %5\n\t"
      "v_pk_fma_f32 %6, v[230:231], v[102:103], %6\n\t"
      "v_pk_fma_f32 %7, v[246:247], v[102:103], %7\n\t"
      "s_waitcnt lgkmcnt(1)\n\t"
      "v_pk_fma_f32 %0, v[136:137], v[104:105], %0\n\t"
      "v_pk_fma_f32 %1, v[152:153], v[104:105], %1\n\t"
      "v_pk_fma_f32 %2, v[168:169], v[104:105], %2\n\t"
      "v_pk_fma_f32 %3, v[184:185], v[104:105], %3\n\t"
      "v_pk_fma_f32 %4, v[200:201], v[104:105], %4\n\t"
      "v_pk_fma_f32 %5, v[216:217], v[104:105], %5\n\t"
      "v_pk_fma_f32 %6, v[232:233], v[104:105], %6\n\t"
      "v_pk_fma_f32 %7, v[248:249], v[104:105], %7\n\t"
      "v_pk_fma_f32 %0, v[138:139], v[106:107], %0\n\t"
      "v_pk_fma_f32 %1, v[154:155], v[106:107], %1\n\t"
      "v_pk_fma_f32 %2, v[170:171], v[106:107], %2\n\t"
      "v_pk_fma_f32 %3, v[186:187], v[106:107], %3\n\t"
      "v_pk_fma_f32 %4, v[202:203], v[106:107], %4\n\t"
      "v_pk_fma_f32 %5, v[218:219], v[106:107], %5\n\t"
      "v_pk_fma_f32 %6, v[234:235], v[106:107], %6\n\t"
      "v_pk_fma_f32 %7, v[250:251], v[106:107], %7\n\t"
      "s_waitcnt lgkmcnt(0)\n\t"
      "v_pk_fma_f32 %0, v[140:141], v[108:109], %0\n\t"
      "v_pk_fma_f32 %1, v[156:157], v[108:109], %1\n\t"
      "v_pk_fma_f32 %2, v[172:173], v[108:109], %2\n\t"
      "v_pk_fma_f32 %3, v[188:189], v[108:109], %3\n\t"
      "v_pk_fma_f32 %4, v[204:205], v[108:109], %4\n\t"
      "v_pk_fma_f32 %5, v[220:221], v[108:109], %5\n\t"
      "v_pk_fma_f32 %6, v[236:237], v[108:109], %6\n\t"
      "v_pk_fma_f32 %7, v[252:253], v[108:109], %7\n\t"
      "v_pk_fma_f32 %0, v[142:143], v[110:111], %0\n\t"
      "v_pk_fma_f32 %1, v[158:159], v[110:111], %1\n\t"
      "v_pk_fma_f32 %2, v[174:175], v[110:111], %2\n\t"
      "v_pk_fma_f32 %3, v[190:191], v[110:111], %3\n\t"
      "v_pk_fma_f32 %4, v[206:207], v[110:111], %4\n\t"
      "v_pk_fma_f32 %5, v[222:223], v[110:111], %5\n\t"
      "v_pk_fma_f32 %6, v[238:239], v[110:111], %6\n\t"
      "v_pk_fma_f32 %7, v[254:255], v[110:111], %7"
      : "=&v"(a0), "=&v"(a1), "=&v"(a2), "=&v"(a3),
        "=&v"(a4), "=&v"(a5), "=&v"(a6), "=&v"(a7)
      : "v"(adr)
      : "v96","v97","v98","v99","v100","v101","v102","v103",
        "v104","v105","v106","v107","v108","v109","v110","v111");

    // collapse pk pairs: s[m] = partial of row (j ^ m)
    float s0 = a0.x + a0.y, s1 = a1.x + a1.y;
    float s2 = a2.x + a2.y, s3 = a3.x + a3.y;
    float s4 = a4.x + a4.y, s5 = a5.x + a5.y;
    float s6 = a6.x + a6.y, s7 = a7.x + a7.y;

    // select-free butterfly reduce (XOR row assignment)
    float r0 = s0 + dpp_xor1(s1);
    float r2 = s2 + dpp_xor1(s3);
    float r4 = s4 + dpp_xor1(s5);
    float r6 = s6 + dpp_xor1(s7);
    float q0 = r0 + dpp_xor2(r2);
    float q4 = r4 + dpp_xor2(r6);
    float x = q0 + swz_xor4(q4) + gcur;   // full preactivation of row j

    // activation: pos==2 -> tanh (as 2*sig(2x)-1), else sigmoid
    float xs = isg ? 2.f * x : x;
    float e = __expf(-xs);
    float r = frcp(1.f + e);
    float a = isg ? 2.f * r - 1.f : r;

    // quad butterfly-GATHER: every lane collects all 4 gate activations
    float b = dpp_xor1(a);
    float c2 = dpp_xor2(a);
    float d2 = dpp_xor2(b);
    float p0 = sw1 ? b : a;
    float p1 = sw1 ? a : b;
    float p2 = sw1 ? d2 : c2;
    float p3 = sw1 ? c2 : d2;
    float i_ = sw2 ? p2 : p0;
    float f_ = sw2 ? p3 : p1;
    float g_ = sw2 ? p0 : p2;
    float o_ = sw2 ? p1 : p3;

    c = __builtin_fmaf(f_, c, i_ * g_);   // all 4 lanes of the quad redundantly
    float h = o_ * ftanh(c);

    pb ^= 1;
    if (pos == 0) {
      hbuf[pb][20 * (unit >> 4) + (unit & 15)] = h;   // skewed layout
      hs[(size_t)step * NF + unit] = h;
    }
    __syncthreads();
  }
}

// ---------------- host launch ----------------

extern "C" void kernel_launch(void* const* d_in, const int* in_sizes, int n_in,
                              void* d_out, int out_size, void* d_ws, size_t ws_size,
                              hipStream_t stream) {
  const float* x     = (const float*)d_in[0];
  const void* edges  = d_in[1];
  const float* W1    = (const float*)d_in[2];
  const float* b1    = (const float*)d_in[3];
  const float* W2    = (const float*)d_in[4];
  const float* b2    = (const float*)d_in[5];
  const float* W_ih  = (const float*)d_in[6];
  const float* W_hh  = (const float*)d_in[7];
  const float* b_ih  = (const float*)d_in[8];
  const float* b_hh  = (const float*)d_in[9];
  const float* W_lin = (const float*)d_in[10];
  const float* b_lin = (const float*)d_in[11];
  float* out = (float*)d_out;

  const int N = in_sizes[0] / NF;  // 20000
  const int E = in_sizes[1] / 2;   // 640000
  const int OUTF = 64;

  char* base = (char*)d_ws;
  size_t off = 0;
  auto alloc = [&](size_t b) {
    char* p = base + off;
    off += (b + 255) & ~(size_t)255;
    return p;
  };
  float* dinv = (float*)alloc((size_t)N * 4);
  float* W1T  = (float*)alloc(128 * 128 * 4);
  float* W2T  = (float*)alloc(128 * 128 * 4);
  float* wp   = (float*)alloc(512 * 128 * 4);
  float* bsum = (float*)alloc(512 * 4);
  int*   flag = (int*)alloc(256);
  float* bufA = (float*)alloc((size_t)N * NF * 4);
  float* bufB = (float*)alloc((size_t)N * NF * 4);
  float* bufC = (float*)alloc((size_t)N * NF * 4);
  float* g_in = (float*)alloc((size_t)N * (size_t)G4 * 4);
  if (off > ws_size) return;

  k_fill<<<(N + 255) / 256, 256, 0, stream>>>(dinv, 1.0f, N);
  k_detect_i64<<<1, 1, 0, stream>>>((const int*)edges, 1024, flag);
  k_count<<<(E + 255) / 256, 256, 0, stream>>>(edges, flag, dinv, E);
  k_rsqrt<<<(N + 255) / 256, 256, 0, stream>>>(dinv, N);
  k_t128<<<128, 128, 0, stream>>>(W1, W1T);
  k_t128<<<128, 128, 0, stream>>>(W2, W2T);
  k_wprep<<<512, 128, 0, stream>>>(W_hh, wp);
  k_add<<<2, 256, 0, stream>>>(b_ih, b_hh, bsum, 512);

  const int mg = (N + 63) / 64;

  gemm_bt<<<dim3(mg, 2), 256, 0, stream>>>(x, W1T, nullptr, bufA, N, NF, NF);
  hipMemsetAsync(bufB, 0, (size_t)N * NF * 4, stream);
  k_aggregate<<<(E + 7) / 8, 256, 0, stream>>>(bufA, edges, flag, dinv, bufB, E);
  k_finish<<<(N * 32 + 255) / 256, 256, 0, stream>>>(bufB, bufA, dinv, b1, N);

  gemm_bt<<<dim3(mg, 2), 256, 0, stream>>>(bufB, W2T, nullptr, bufA, N, NF, NF);
  hipMemsetAsync(bufC, 0, (size_t)N * NF * 4, stream);
  k_aggregate<<<(E + 7) / 8, 256, 0, stream>>>(bufA, edges, flag, dinv, bufC, E);
  k_finish<<<(N * 32 + 255) / 256, 256, 0, stream>>>(bufC, bufA, dinv, b2, N);

  gemm_bt<<<dim3(mg, 8), 256, 0, stream>>>(bufC, W_ih, bsum, g_in, N, G4, NF);

  k_lstm<<<1, 512, 0, stream>>>(g_in, wp, bufB, N);

  gemm_bt<<<dim3(mg, 1), 256, 0, stream>>>(bufB, W_lin, b_lin, out, N, OUTF, NF);
}

// Round 13
// 12697.196 us; speedup vs baseline: 1.1803x; 1.1803x over previous
//
#include <hip/hip_runtime.h>
#include <cstdint>

#define NF 128   // node feature / hidden width
#define G4 512   // 4*H gates

// ---------------- small utility kernels ----------------

__global__ void k_fill(float* p, float v, int n) {
  int i = blockIdx.x * blockDim.x + threadIdx.x;
  if (i < n) p[i] = v;
}

__global__ void k_detect_i64(const int* e, int npairs, int* flag) {
  int f = 1;
  for (int i = 1; i < 2 * npairs; i += 2)
    if (e[i] != 0) { f = 0; break; }
  *flag = f;
}

__device__ __forceinline__ int eidx(const void* edges, int i64, size_t pos) {
  if (i64) return (int)((const long long*)edges)[pos];
  return ((const int*)edges)[pos];
}

__global__ void k_count(const void* __restrict__ edges, const int* __restrict__ flag,
                        float* __restrict__ deg, int E) {
  int e = blockIdx.x * blockDim.x + threadIdx.x;
  if (e < E) {
    int d = eidx(edges, *flag, (size_t)E + e);
    unsafeAtomicAdd(&deg[d], 1.0f);
  }
}

__global__ void k_rsqrt(float* p, int n) {
  int i = blockIdx.x * blockDim.x + threadIdx.x;
  if (i < n) p[i] = rsqrtf(p[i]);
}

__global__ void k_t128(const float* __restrict__ in, float* __restrict__ out) {
  int n = blockIdx.x, k = threadIdx.x;
  out[n * 128 + k] = in[k * 128 + n];
}

__global__ void k_add(const float* a, const float* b, float* o, int n) {
  int i = blockIdx.x * blockDim.x + threadIdx.x;
  if (i < n) o[i] = a[i] + b[i];
}

// Weight prep for the 8-lane-group LSTM layout (verified R9/R10).
// Lane t: j = t&7, group g8 = t>>3 owns units {2g8, 2g8+1}.
// Chain m of lane t computes the partial of group-row (j^m) over cols
// [16j, 16j+16). Gate order in rows: 0=i 1=f 2=g 3=o (PyTorch chunk order).
__global__ void k_wprep(const float* __restrict__ W, float* __restrict__ wp) {
  int t = blockIdx.x;        // 0..511
  int m = threadIdx.x;       // 0..127
  int j = t & 7;
  int g8 = t >> 3;
  int blk = m >> 4;          // chain index 0..7
  int k = m & 15;
  int rr = j ^ blk;          // row within group
  int gate = rr & 3, du = rr >> 2;
  int unit = 2 * g8 + du;
  int col = 16 * j + k;
  wp[(size_t)t * 128 + m] = W[(size_t)(gate * 128 + unit) * 128 + col];
}

// ---------------- GEMM: C[M,N] = A[M,K] @ B[N,K]^T (+bias) ----------------
__global__ __launch_bounds__(256)
void gemm_bt(const float* __restrict__ A, const float* __restrict__ B,
             const float* __restrict__ bias, float* __restrict__ C,
             int M, int N, int K) {
  __shared__ float As[32][68];
  __shared__ float Bs[32][68];
  const int bm = blockIdx.x * 64;
  const int bn = blockIdx.y * 64;
  const int tid = threadIdx.x;
  const int tm = (tid & 15) << 2;
  const int tn = (tid >> 4) << 2;
  float acc[4][4] = {};

  for (int k0 = 0; k0 < K; k0 += 32) {
#pragma unroll
    for (int l = 0; l < 2; ++l) {
      int idx = tid + l * 256;
      int row = idx >> 3;
      int k4 = (idx & 7) << 2;
      int ar = bm + row; ar = ar < M ? ar : M - 1;
      float4 av = *(const float4*)(A + (size_t)ar * K + k0 + k4);
      As[k4 + 0][row] = av.x; As[k4 + 1][row] = av.y;
      As[k4 + 2][row] = av.z; As[k4 + 3][row] = av.w;
      int br = bn + row; br = br < N ? br : N - 1;
      float4 bv = *(const float4*)(B + (size_t)br * K + k0 + k4);
      Bs[k4 + 0][row] = bv.x; Bs[k4 + 1][row] = bv.y;
      Bs[k4 + 2][row] = bv.z; Bs[k4 + 3][row] = bv.w;
    }
    __syncthreads();
#pragma unroll
    for (int kk = 0; kk < 32; ++kk) {
      float4 a = *(const float4*)&As[kk][tm];
      float4 b = *(const float4*)&Bs[kk][tn];
      float av[4] = {a.x, a.y, a.z, a.w};
      float bv[4] = {b.x, b.y, b.z, b.w};
#pragma unroll
      for (int i = 0; i < 4; ++i)
#pragma unroll
        for (int jj = 0; jj < 4; ++jj)
          acc[i][jj] = __builtin_fmaf(av[i], bv[jj], acc[i][jj]);
    }
    __syncthreads();
  }

  float4 bv4;
  if (bias) bv4 = *(const float4*)(bias + bn + tn);
  else bv4 = make_float4(0.f, 0.f, 0.f, 0.f);
#pragma unroll
  for (int i = 0; i < 4; ++i) {
    int row = bm + tm + i;
    if (row < M) {
      float4 v;
      v.x = acc[i][0] + bv4.x;
      v.y = acc[i][1] + bv4.y;
      v.z = acc[i][2] + bv4.z;
      v.w = acc[i][3] + bv4.w;
      *(float4*)(C + (size_t)row * N + bn + tn) = v;
    }
  }
}

// ---------------- GCN edge aggregation (atomic scatter) ----------------
__global__ __launch_bounds__(256)
void k_aggregate(const float* __restrict__ xw, const void* __restrict__ edges,
                 const int* __restrict__ flag, const float* __restrict__ dinv,
                 float* __restrict__ out, int E) {
  int e = blockIdx.x * 8 + (threadIdx.x >> 5);
  if (e >= E) return;
  int i64 = *flag;
  int s = eidx(edges, i64, e);
  int d = eidx(edges, i64, (size_t)E + e);
  float nrm = dinv[s] * dinv[d];
  int f4 = threadIdx.x & 31;
  float4 v = ((const float4*)xw)[(size_t)s * 32 + f4];
  float* op = out + (size_t)d * 128 + f4 * 4;
  unsafeAtomicAdd(op + 0, v.x * nrm);
  unsafeAtomicAdd(op + 1, v.y * nrm);
  unsafeAtomicAdd(op + 2, v.z * nrm);
  unsafeAtomicAdd(op + 3, v.w * nrm);
}

__global__ void k_finish(float* __restrict__ h, const float* __restrict__ xw,
                         const float* __restrict__ dinv, const float* __restrict__ b,
                         int N) {
  int i4 = blockIdx.x * blockDim.x + threadIdx.x;
  if (i4 >= N * 32) return;
  int n = i4 >> 5;
  int f4 = (i4 & 31) << 2;
  float di = dinv[n];
  float s = di * di;
  float4 ag = ((const float4*)h)[i4];
  float4 xv = ((const float4*)xw)[i4];
  float4 bv = *(const float4*)(b + f4);
  float4 r;
  r.x = fmaxf(__builtin_fmaf(xv.x, s, ag.x) + bv.x, 0.f);
  r.y = fmaxf(__builtin_fmaf(xv.y, s, ag.y) + bv.y, 0.f);
  r.z = fmaxf(__builtin_fmaf(xv.z, s, ag.z) + bv.z, 0.f);
  r.w = fmaxf(__builtin_fmaf(xv.w, s, ag.w) + bv.w, 0.f);
  ((float4*)h)[i4] = r;
}

// ---------------- sequential LSTM scan: WHOLE LOOP IN ONE ASM BLOCK -------
// R11/R12 NaN root cause (found R13): loop-carried operands were "+v"
// WITHOUT early-clobber. The asm writes outputs (ga/gb/gio/hso/cc) in the
// prologue and every iteration while re-reading inputs (ar0/ar1/w0/w1/...)
// every iteration -- but without '&' LLVM may allocate an INPUT into the
// same physreg as an output (it assumes inputs are consumed before outputs
// are written). First global_load into ga could corrupt e.g. w1 -> NaN.
// Fix: all loop-carried operands are "=&v"/"=&s" (early-clobber) with
// matching-constraint tied inputs -> inputs provably disjoint from outputs.
// Also: s_nop 1 after each trans op (v_exp/v_rcp) before its consumer.

#define DS_READS(ADR) \
  "ds_read_b128 v[96:99], %[" ADR "]\n\t" \
  "ds_read_b128 v[100:103], %[" ADR "] offset:16\n\t" \
  "ds_read_b128 v[104:107], %[" ADR "] offset:32\n\t" \
  "ds_read_b128 v[108:111], %[" ADR "] offset:48\n\t"

#define FMACORE \
  "s_waitcnt lgkmcnt(3)\n\t" \
  "v_pk_mul_f32 v[64:65], v[128:129], v[96:97]\n\t" \
  "v_pk_mul_f32 v[66:67], v[144:145], v[96:97]\n\t" \
  "v_pk_mul_f32 v[68:69], v[160:161], v[96:97]\n\t" \
  "v_pk_mul_f32 v[70:71], v[176:177], v[96:97]\n\t" \
  "v_pk_mul_f32 v[72:73], v[192:193], v[96:97]\n\t" \
  "v_pk_mul_f32 v[74:75], v[208:209], v[96:97]\n\t" \
  "v_pk_mul_f32 v[76:77], v[224:225], v[96:97]\n\t" \
  "v_pk_mul_f32 v[78:79], v[240:241], v[96:97]\n\t" \
  "v_pk_fma_f32 v[64:65], v[130:131], v[98:99], v[64:65]\n\t" \
  "v_pk_fma_f32 v[66:67], v[146:147], v[98:99], v[66:67]\n\t" \
  "v_pk_fma_f32 v[68:69], v[162:163], v[98:99], v[68:69]\n\t" \
  "v_pk_fma_f32 v[70:71], v[178:179], v[98:99], v[70:71]\n\t" \
  "v_pk_fma_f32 v[72:73], v[194:195], v[98:99], v[72:73]\n\t" \
  "v_pk_fma_f32 v[74:75], v[210:211], v[98:99], v[74:75]\n\t" \
  "v_pk_fma_f32 v[76:77], v[226:227], v[98:99], v[76:77]\n\t" \
  "v_pk_fma_f32 v[78:79], v[242:243], v[98:99], v[78:79]\n\t" \
  "s_waitcnt lgkmcnt(2)\n\t" \
  "v_pk_fma_f32 v[64:65], v[132:133], v[100:101], v[64:65]\n\t" \
  "v_pk_fma_f32 v[66:67], v[148:149], v[100:101], v[66:67]\n\t" \
  "v_pk_fma_f32 v[68:69], v[164:165], v[100:101], v[68:69]\n\t" \
  "v_pk_fma_f32 v[70:71], v[180:181], v[100:101], v[70:71]\n\t" \
  "v_pk_fma_f32 v[72:73], v[196:197], v[100:101], v[72:73]\n\t" \
  "v_pk_fma_f32 v[74:75], v[212:213], v[100:101], v[74:75]\n\t" \
  "v_pk_fma_f32 v[76:77], v[228:229], v[100:101], v[76:77]\n\t" \
  "v_pk_fma_f32 v[78:79], v[244:245], v[100:101], v[78:79]\n\t" \
  "v_pk_fma_f32 v[64:65], v[134:135], v[102:103], v[64:65]\n\t" \
  "v_pk_fma_f32 v[66:67], v[150:151], v[102:103], v[66:67]\n\t" \
  "v_pk_fma_f32 v[68:69], v[166:167], v[102:103], v[68:69]\n\t" \
  "v_pk_fma_f32 v[70:71], v[182:183], v[102:103], v[70:71]\n\t" \
  "v_pk_fma_f32 v[72:73], v[198:199], v[102:103], v[72:73]\n\t" \
  "v_pk_fma_f32 v[74:75], v[214:215], v[102:103], v[74:75]\n\t" \
  "v_pk_fma_f32 v[76:77], v[230:231], v[102:103], v[76:77]\n\t" \
  "v_pk_fma_f32 v[78:79], v[246:247], v[102:103], v[78:79]\n\t" \
  "s_waitcnt lgkmcnt(1)\n\t" \
  "v_pk_fma_f32 v[64:65], v[136:137], v[104:105], v[64:65]\n\t" \
  "v_pk_fma_f32 v[66:67], v[152:153], v[104:105], v[66:67]\n\t" \
  "v_pk_fma_f32 v[68:69], v[168:169], v[104:105], v[68:69]\n\t" \
  "v_pk_fma_f32 v[70:71], v[184:185], v[104:105], v[70:71]\n\t" \
  "v_pk_fma_f32 v[72:73], v[200:201], v[104:105], v[72:73]\n\t" \
  "v_pk_fma_f32 v[74:75], v[216:217], v[104:105], v[74:75]\n\t" \
  "v_pk_fma_f32 v[76:77], v[232:233], v[104:105], v[76:77]\n\t" \
  "v_pk_fma_f32 v[78:79], v[248:249], v[104:105], v[78:79]\n\t" \
  "v_pk_fma_f32 v[64:65], v[138:139], v[106:107], v[64:65]\n\t" \
  "v_pk_fma_f32 v[66:67], v[154:155], v[106:107], v[66:67]\n\t" \
  "v_pk_fma_f32 v[68:69], v[170:171], v[106:107], v[68:69]\n\t" \
  "v_pk_fma_f32 v[70:71], v[186:187], v[106:107], v[70:71]\n\t" \
  "v_pk_fma_f32 v[72:73], v[202:203], v[106:107], v[72:73]\n\t" \
  "v_pk_fma_f32 v[74:75], v[218:219], v[106:107], v[74:75]\n\t" \
  "v_pk_fma_f32 v[76:77], v[234:235], v[106:107], v[76:77]\n\t" \
  "v_pk_fma_f32 v[78:79], v[250:251], v[106:107], v[78:79]\n\t" \
  "s_waitcnt lgkmcnt(0)\n\t" \
  "v_pk_fma_f32 v[64:65], v[140:141], v[108:109], v[64:65]\n\t" \
  "v_pk_fma_f32 v[66:67], v[156:157], v[108:109], v[66:67]\n\t" \
  "v_pk_fma_f32 v[68:69], v[172:173], v[108:109], v[68:69]\n\t" \
  "v_pk_fma_f32 v[70:71], v[188:189], v[108:109], v[70:71]\n\t" \
  "v_pk_fma_f32 v[72:73], v[204:205], v[108:109], v[72:73]\n\t" \
  "v_pk_fma_f32 v[74:75], v[220:221], v[108:109], v[74:75]\n\t" \
  "v_pk_fma_f32 v[76:77], v[236:237], v[108:109], v[76:77]\n\t" \
  "v_pk_fma_f32 v[78:79], v[252:253], v[108:109], v[78:79]\n\t" \
  "v_pk_fma_f32 v[64:65], v[142:143], v[110:111], v[64:65]\n\t" \
  "v_pk_fma_f32 v[66:67], v[158:159], v[110:111], v[66:67]\n\t" \
  "v_pk_fma_f32 v[68:69], v[174:175], v[110:111], v[68:69]\n\t" \
  "v_pk_fma_f32 v[70:71], v[190:191], v[110:111], v[70:71]\n\t" \
  "v_pk_fma_f32 v[72:73], v[206:207], v[110:111], v[72:73]\n\t" \
  "v_pk_fma_f32 v[74:75], v[222:223], v[110:111], v[74:75]\n\t" \
  "v_pk_fma_f32 v[76:77], v[238:239], v[110:111], v[76:77]\n\t" \
  "v_pk_fma_f32 v[78:79], v[254:255], v[110:111], v[78:79]\n\t"

// collapse + select-free butterfly (DPP src modifier; s_nop for DPP hazards)
// vmcnt(1): with {L_old,S,L_old2,S} outstanding, >=3 retired must include
// the oldest load (in-order) -> the 2-step-old load is complete.
#define REDUCE_FIXED \
  "v_add_f32 v80, v64, v65\n\t" \
  "v_add_f32 v81, v66, v67\n\t" \
  "v_add_f32 v82, v68, v69\n\t" \
  "v_add_f32 v83, v70, v71\n\t" \
  "v_add_f32 v84, v72, v73\n\t" \
  "v_add_f32 v85, v74, v75\n\t" \
  "v_add_f32 v86, v76, v77\n\t" \
  "v_add_f32 v87, v78, v79\n\t" \
  "v_add_f32 v88, v81, v80 quad_perm:[1,0,3,2] row_mask:0xf bank_mask:0xf\n\t" \
  "v_add_f32 v89, v83, v82 quad_perm:[1,0,3,2] row_mask:0xf bank_mask:0xf\n\t" \
  "v_add_f32 v90, v85, v84 quad_perm:[1,0,3,2] row_mask:0xf bank_mask:0xf\n\t" \
  "v_add_f32 v91, v87, v86 quad_perm:[1,0,3,2] row_mask:0xf bank_mask:0xf\n\t" \
  "v_add_f32 v92, v89, v88 quad_perm:[2,3,0,1] row_mask:0xf bank_mask:0xf\n\t" \
  "s_nop 0\n\t" \
  "v_add_f32 v93, v91, v90 quad_perm:[2,3,0,1] row_mask:0xf bank_mask:0xf\n\t" \
  "ds_swizzle_b32 v94, v93 offset:0x101F\n\t" \
  "s_waitcnt vmcnt(1)\n\t"

#define GLOAD(GX) \
  "v_add_f32 v92, v92, %[" GX "]\n\t" \
  "s_waitcnt lgkmcnt(0)\n\t" \
  "v_add_f32 v92, v92, v94\n\t" \
  "global_load_dword %[" GX "], %[gio], %[gin]\n\t" \
  "v_add_u32 %[gio], 0x800, %[gio]\n\t"

// activation (per-lane consts) + gate combine via DPP products + c/h update
#define ACT_CH \
  "v_mul_f32 v80, %[kexp], v92\n\t" \
  "v_exp_f32 v80, v80\n\t" \
  "s_nop 1\n\t" \
  "v_add_f32 v80, 1.0, v80\n\t" \
  "v_rcp_f32 v80, v80\n\t" \
  "s_nop 1\n\t" \
  "v_fma_f32 v81, v80, %[sA], %[sB]\n\t" \
  "s_nop 1\n\t" \
  "v_mul_f32 v82, v81, v81 quad_perm:[2,3,0,1] row_mask:0xf bank_mask:0xf\n\t" \
  "v_mov_b32 v83, v81 quad_perm:[1,1,1,1] row_mask:0xf bank_mask:0xf\n\t" \
  "v_mov_b32 v84, v81 quad_perm:[3,3,3,3] row_mask:0xf bank_mask:0xf\n\t" \
  "v_mov_b32 v85, v82 quad_perm:[1,0,3,2] row_mask:0xf bank_mask:0xf\n\t" \
  "s_nop 0\n\t" \
  "v_cndmask_b32 v85, v82, v85, %[modd]\n\t" \
  "v_fma_f32 %[cc], v83, %[cc], v85\n\t" \
  "v_mul_f32 v86, 0x4038aa3b, %[cc]\n\t" \
  "v_exp_f32 v86, v86\n\t" \
  "s_nop 1\n\t" \
  "v_add_f32 v86, 1.0, v86\n\t" \
  "v_rcp_f32 v86, v86\n\t" \
  "s_nop 1\n\t" \
  "v_mul_f32 v87, v84, v86\n\t" \
  "v_fma_f32 v87, -2.0, v87, v84\n\t"

#define HSTORE(WW) \
  "s_mov_b64 exec, %[m0q]\n\t" \
  "ds_write_b32 %[" WW "], v87\n\t" \
  "global_store_dword %[hso], v87, %[hsb]\n\t" \
  "s_mov_b64 exec, -1\n\t" \
  "v_add_u32 %[hso], 0x200, %[hso]\n\t" \
  "s_waitcnt lgkmcnt(0)\n\t" \
  "s_barrier\n\t"

__global__ __launch_bounds__(512)
__attribute__((amdgpu_waves_per_eu(2, 2)))
void k_lstm(const float* __restrict__ g_in, const float* __restrict__ wp,
            float* __restrict__ hs, int T) {
  const int t = threadIdx.x;
  const int j = t & 7;
  const int g8 = t >> 3;
  const int pos = t & 3;               // gate: 0=i 1=f 2=g 3=o
  const int du = (t >> 2) & 1;
  const int unit = 2 * g8 + du;
  const int row = pos * 128 + unit;
  const bool isg = (pos == 2);

  __shared__ __align__(16) float hbuf[2][160];
  __shared__ float lds_cap[20736];     // 82944 B occupancy anchor

  if (t == 0) {
    volatile float* vp = lds_cap;
    vp[0] = 0.f;
  }
  if (t < 160) { hbuf[0][t] = 0.f; hbuf[1][t] = 0.f; }

  // ---- ALL setup BEFORE the preload asm ----
  uint32_t ar0 = (uint32_t)(uintptr_t)&hbuf[0][20 * j];
  uint32_t ar1 = (uint32_t)(uintptr_t)&hbuf[1][20 * j];
  uint32_t w0  = (uint32_t)(uintptr_t)&hbuf[0][20 * (unit >> 4) + (unit & 15)];
  uint32_t w1  = (uint32_t)(uintptr_t)&hbuf[1][20 * (unit >> 4) + (unit & 15)];
  uint32_t gio = (uint32_t)(row * 4);
  uint32_t hso = (uint32_t)(unit * 4);
  float kexp = isg ? -2.8853900817779268f : -1.4426950408889634f;
  float sA   = isg ? 2.f : 1.f;
  float sB   = isg ? -1.f : 0.f;
  unsigned long long m0q  = __ballot(pos == 0);
  unsigned long long modd = __ballot((pos & 1) != 0);
  float cc = 0.f, ga = 0.f, gb = 0.f;
  int cnt = T >> 1;                     // T is even (20000)
  const float* wr = wp + (size_t)t * 128;

  // -------- one-time weight preload into physical v128..v255 --------
  asm volatile(
    "global_load_dwordx4 v[128:131], %0, off\n\t"
    "global_load_dwordx4 v[132:135], %0, off offset:16\n\t"
    "global_load_dwordx4 v[136:139], %0, off offset:32\n\t"
    "global_load_dwordx4 v[140:143], %0, off offset:48\n\t"
    "global_load_dwordx4 v[144:147], %0, off offset:64\n\t"
    "global_load_dwordx4 v[148:151], %0, off offset:80\n\t"
    "global_load_dwordx4 v[152:155], %0, off offset:96\n\t"
    "global_load_dwordx4 v[156:159], %0, off offset:112\n\t"
    "global_load_dwordx4 v[160:163], %0, off offset:128\n\t"
    "global_load_dwordx4 v[164:167], %0, off offset:144\n\t"
    "global_load_dwordx4 v[168:171], %0, off offset:160\n\t"
    "global_load_dwordx4 v[172:175], %0, off offset:176\n\t"
    "global_load_dwordx4 v[176:179], %0, off offset:192\n\t"
    "global_load_dwordx4 v[180:183], %0, off offset:208\n\t"
    "global_load_dwordx4 v[184:187], %0, off offset:224\n\t"
    "global_load_dwordx4 v[188:191], %0, off offset:240\n\t"
    "global_load_dwordx4 v[192:195], %0, off offset:256\n\t"
    "global_load_dwordx4 v[196:199], %0, off offset:272\n\t"
    "global_load_dwordx4 v[200:203], %0, off offset:288\n\t"
    "global_load_dwordx4 v[204:207], %0, off offset:304\n\t"
    "global_load_dwordx4 v[208:211], %0, off offset:320\n\t"
    "global_load_dwordx4 v[212:215], %0, off offset:336\n\t"
    "global_load_dwordx4 v[216:219], %0, off offset:352\n\t"
    "global_load_dwordx4 v[220:223], %0, off offset:368\n\t"
    "global_load_dwordx4 v[224:227], %0, off offset:384\n\t"
    "global_load_dwordx4 v[228:231], %0, off offset:400\n\t"
    "global_load_dwordx4 v[232:235], %0, off offset:416\n\t"
    "global_load_dwordx4 v[236:239], %0, off offset:432\n\t"
    "global_load_dwordx4 v[240:243], %0, off offset:448\n\t"
    "global_load_dwordx4 v[244:247], %0, off offset:464\n\t"
    "global_load_dwordx4 v[248:251], %0, off offset:480\n\t"
    "global_load_dwordx4 v[252:255], %0, off offset:496\n\t"
    "s_waitcnt vmcnt(0)"
    :: "v"(wr)
    : "v128","v129","v130","v131","v132","v133","v134","v135",
      "v136","v137","v138","v139","v140","v141","v142","v143",
      "v144","v145","v146","v147","v148","v149","v150","v151",
      "v152","v153","v154","v155","v156","v157","v158","v159",
      "v160","v161","v162","v163","v164","v165","v166","v167",
      "v168","v169","v170","v171","v172","v173","v174","v175",
      "v176","v177","v178","v179","v180","v181","v182","v183",
      "v184","v185","v186","v187","v188","v189","v190","v191",
      "v192","v193","v194","v195","v196","v197","v198","v199",
      "v200","v201","v202","v203","v204","v205","v206","v207",
      "v208","v209","v210","v211","v212","v213","v214","v215",
      "v216","v217","v218","v219","v220","v221","v222","v223",
      "v224","v225","v226","v227","v228","v229","v230","v231",
      "v232","v233","v234","v235","v236","v237","v238","v239",
      "v240","v241","v242","v243","v244","v245","v246","v247",
      "v248","v249","v250","v251","v252","v253","v254","v255");

  __syncthreads();

  asm volatile(
    // prologue: load g rows for steps 0,1; advance gio to step 2
    "global_load_dword %[ga], %[gio], %[gin]\n\t"
    "v_add_u32 %[gio], 0x800, %[gio]\n\t"
    "global_load_dword %[gb], %[gio], %[gin]\n\t"
    "v_add_u32 %[gio], 0x800, %[gio]\n\t"
    "s_waitcnt vmcnt(0)\n\t"
    "Lscan%=:\n\t"
    // ---- half A: even step, read buf0, write buf1, uses ga ----
    DS_READS("ar0")
    FMACORE
    REDUCE_FIXED
    GLOAD("ga")
    ACT_CH
    HSTORE("w1")
    // ---- half B: odd step, read buf1, write buf0, uses gb ----
    DS_READS("ar1")
    FMACORE
    REDUCE_FIXED
    GLOAD("gb")
    ACT_CH
    HSTORE("w0")
    // loop control
    "s_sub_u32 %[cnt], %[cnt], 1\n\t"
    "s_cmp_lg_u32 %[cnt], 0\n\t"
    "s_cbranch_scc1 Lscan%=\n\t"
    : [cc]"=&v"(cc), [ga]"=&v"(ga), [gb]"=&v"(gb),
      [gio]"=&v"(gio), [hso]"=&v"(hso), [cnt]"=&s"(cnt)
    : [gin]"s"(g_in), [hsb]"s"(hs),
      [m0q]"s"(m0q), [modd]"s"(modd),
      [ar0]"v"(ar0), [ar1]"v"(ar1), [w0]"v"(w0), [w1]"v"(w1),
      [kexp]"v"(kexp), [sA]"v"(sA), [sB]"v"(sB),
      "0"(cc), "1"(ga), "2"(gb), "3"(gio), "4"(hso), "5"(cnt)
    : "memory", "scc",
      "v64","v65","v66","v67","v68","v69","v70","v71",
      "v72","v73","v74","v75","v76","v77","v78","v79",
      "v80","v81","v82","v83","v84","v85","v86","v87",
      "v88","v89","v90","v91","v92","v93","v94","v95",
      "v96","v97","v98","v99","v100","v101","v102","v103",
      "v104","v105","v106","v107","v108","v109","v110","v111",
      "v128","v129","v130","v131","v132","v133","v134","v135",
      "v136","v137","v138","v139","v140","v141","v142","v143",
      "v144","v145","v146","v147","v148","v149","v150","v151",
      "v152","v153","v154","v155","v156","v157","v158","v159",
      "v160","v161","v162","v163","v164","v165","v166","v167",
      "v168","v169","v170","v171","v172","v173","v174","v175",
      "v176","v177","v178","v179","v180","v181","v182","v183",
      "v184","v185","v186","v187","v188","v189","v190","v191",
      "v192","v193","v194","v195","v196","v197","v198","v199",
      "v200","v201","v202","v203","v204","v205","v206","v207",
      "v208","v209","v210","v211","v212","v213","v214","v215",
      "v216","v217","v218","v219","v220","v221","v222","v223",
      "v224","v225","v226","v227","v228","v229","v230","v231",
      "v232","v233","v234","v235","v236","v237","v238","v239",
      "v240","v241","v242","v243","v244","v245","v246","v247",
      "v248","v249","v250","v251","v252","v253","v254","v255");
}

// ---------------- host launch ----------------

extern "C" void kernel_launch(void* const* d_in, const int* in_sizes, int n_in,
                              void* d_out, int out_size, void* d_ws, size_t ws_size,
                              hipStream_t stream) {
  const float* x     = (const float*)d_in[0];
  const void* edges  = d_in[1];
  const float* W1    = (const float*)d_in[2];
  const float* b1    = (const float*)d_in[3];
  const float* W2    = (const float*)d_in[4];
  const float* b2    = (const float*)d_in[5];
  const float* W_ih  = (const float*)d_in[6];
  const float* W_hh  = (const float*)d_in[7];
  const float* b_ih  = (const float*)d_in[8];
  const float* b_hh  = (const float*)d_in[9];
  const float* W_lin = (const float*)d_in[10];
  const float* b_lin = (const float*)d_in[11];
  float* out = (float*)d_out;

  const int N = in_sizes[0] / NF;  // 20000
  const int E = in_sizes[1] / 2;   // 640000
  const int OUTF = 64;

  char* base = (char*)d_ws;
  size_t off = 0;
  auto alloc = [&](size_t b) {
    char* p = base + off;
    off += (b + 255) & ~(size_t)255;
    return p;
  };
  float* dinv = (float*)alloc((size_t)N * 4);
  float* W1T  = (float*)alloc(128 * 128 * 4);
  float* W2T  = (float*)alloc(128 * 128 * 4);
  float* wp   = (float*)alloc(512 * 128 * 4);
  float* bsum = (float*)alloc(512 * 4);
  int*   flag = (int*)alloc(256);
  float* bufA = (float*)alloc((size_t)N * NF * 4);
  float* bufB = (float*)alloc((size_t)N * NF * 4);
  float* bufC = (float*)alloc((size_t)N * NF * 4);
  float* g_in = (float*)alloc(((size_t)N + 4) * (size_t)G4 * 4);  // +4 rows slack (prefetch OOB)
  if (off > ws_size) return;

  k_fill<<<(N + 255) / 256, 256, 0, stream>>>(dinv, 1.0f, N);
  k_detect_i64<<<1, 1, 0, stream>>>((const int*)edges, 1024, flag);
  k_count<<<(E + 255) / 256, 256, 0, stream>>>(edges, flag, dinv, E);
  k_rsqrt<<<(N + 255) / 256, 256, 0, stream>>>(dinv, N);
  k_t128<<<128, 128, 0, stream>>>(W1, W1T);
  k_t128<<<128, 128, 0, stream>>>(W2, W2T);
  k_wprep<<<512, 128, 0, stream>>>(W_hh, wp);
  k_add<<<2, 256, 0, stream>>>(b_ih, b_hh, bsum, 512);

  const int mg = (N + 63) / 64;

  gemm_bt<<<dim3(mg, 2), 256, 0, stream>>>(x, W1T, nullptr, bufA, N, NF, NF);
  hipMemsetAsync(bufB, 0, (size_t)N * NF * 4, stream);
  k_aggregate<<<(E + 7) / 8, 256, 0, stream>>>(bufA, edges, flag, dinv, bufB, E);
  k_finish<<<(N * 32 + 255) / 256, 256, 0, stream>>>(bufB, bufA, dinv, b1, N);

  gemm_bt<<<dim3(mg, 2), 256, 0, stream>>>(bufB, W2T, nullptr, bufA, N, NF, NF);
  hipMemsetAsync(bufC, 0, (size_t)N * NF * 4, stream);
  k_aggregate<<<(E + 7) / 8, 256, 0, stream>>>(bufA, edges, flag, dinv, bufC, E);
  k_finish<<<(N * 32 + 255) / 256, 256, 0, stream>>>(bufC, bufA, dinv, b2, N);

  gemm_bt<<<dim3(mg, 8), 256, 0, stream>>>(bufC, W_ih, bsum, g_in, N, G4, NF);

  k_lstm<<<1, 512, 0, stream>>>(g_in, wp, bufB, N);

  gemm_bt<<<dim3(mg, 1), 256, 0, stream>>>(bufB, W_lin, b_lin, out, N, OUTF, NF);
}

// Round 16
// 12261.932 us; speedup vs baseline: 1.2222x; 1.0355x over previous
//
#include <hip/hip_runtime.h>
#include <cstdint>

#define NF 128   // node feature / hidden width
#define G4 512   // 4*H gates

// ---------------- small utility kernels ----------------

__global__ void k_fill(float* p, float v, int n) {
  int i = blockIdx.x * blockDim.x + threadIdx.x;
  if (i < n) p[i] = v;
}

__global__ void k_detect_i64(const int* e, int npairs, int* flag) {
  int f = 1;
  for (int i = 1; i < 2 * npairs; i += 2)
    if (e[i] != 0) { f = 0; break; }
  *flag = f;
}

__device__ __forceinline__ int eidx(const void* edges, int i64, size_t pos) {
  if (i64) return (int)((const long long*)edges)[pos];
  return ((const int*)edges)[pos];
}

__global__ void k_count(const void* __restrict__ edges, const int* __restrict__ flag,
                        float* __restrict__ deg, int E) {
  int e = blockIdx.x * blockDim.x + threadIdx.x;
  if (e < E) {
    int d = eidx(edges, *flag, (size_t)E + e);
    unsafeAtomicAdd(&deg[d], 1.0f);
  }
}

__global__ void k_rsqrt(float* p, int n) {
  int i = blockIdx.x * blockDim.x + threadIdx.x;
  if (i < n) p[i] = rsqrtf(p[i]);
}

__global__ void k_t128(const float* __restrict__ in, float* __restrict__ out) {
  int n = blockIdx.x, k = threadIdx.x;
  out[n * 128 + k] = in[k * 128 + n];
}

__global__ void k_add(const float* a, const float* b, float* o, int n) {
  int i = blockIdx.x * blockDim.x + threadIdx.x;
  if (i < n) o[i] = a[i] + b[i];
}

// Weight prep for the 8-lane-group LSTM layout (verified R9-R13).
// Lane t: j = t&7, group g8 = t>>3 owns units {2g8, 2g8+1}.
// Chain m of lane t computes the partial of group-row (j^m) over cols
// [16j, 16j+16). Gate order in rows: 0=i 1=f 2=g 3=o (PyTorch chunk order).
__global__ void k_wprep(const float* __restrict__ W, float* __restrict__ wp) {
  int t = blockIdx.x;        // 0..511
  int m = threadIdx.x;       // 0..127
  int j = t & 7;
  int g8 = t >> 3;
  int blk = m >> 4;          // chain index 0..7
  int k = m & 15;
  int rr = j ^ blk;          // row within group
  int gate = rr & 3, du = rr >> 2;
  int unit = 2 * g8 + du;
  int col = 16 * j + k;
  wp[(size_t)t * 128 + m] = W[(size_t)(gate * 128 + unit) * 128 + col];
}

// ---------------- GEMM: C[M,N] = A[M,K] @ B[N,K]^T (+bias) ----------------
__global__ __launch_bounds__(256)
void gemm_bt(const float* __restrict__ A, const float* __restrict__ B,
             const float* __restrict__ bias, float* __restrict__ C,
             int M, int N, int K) {
  __shared__ float As[32][68];
  __shared__ float Bs[32][68];
  const int bm = blockIdx.x * 64;
  const int bn = blockIdx.y * 64;
  const int tid = threadIdx.x;
  const int tm = (tid & 15) << 2;
  const int tn = (tid >> 4) << 2;
  float acc[4][4] = {};

  for (int k0 = 0; k0 < K; k0 += 32) {
#pragma unroll
    for (int l = 0; l < 2; ++l) {
      int idx = tid + l * 256;
      int row = idx >> 3;
      int k4 = (idx & 7) << 2;
      int ar = bm + row; ar = ar < M ? ar : M - 1;
      float4 av = *(const float4*)(A + (size_t)ar * K + k0 + k4);
      As[k4 + 0][row] = av.x; As[k4 + 1][row] = av.y;
      As[k4 + 2][row] = av.z; As[k4 + 3][row] = av.w;
      int br = bn + row; br = br < N ? br : N - 1;
      float4 bv = *(const float4*)(B + (size_t)br * K + k0 + k4);
      Bs[k4 + 0][row] = bv.x; Bs[k4 + 1][row] = bv.y;
      Bs[k4 + 2][row] = bv.z; Bs[k4 + 3][row] = bv.w;
    }
    __syncthreads();
#pragma unroll
    for (int kk = 0; kk < 32; ++kk) {
      float4 a = *(const float4*)&As[kk][tm];
      float4 b = *(const float4*)&Bs[kk][tn];
      float av[4] = {a.x, a.y, a.z, a.w};
      float bv[4] = {b.x, b.y, b.z, b.w};
#pragma unroll
      for (int i = 0; i < 4; ++i)
#pragma unroll
        for (int jj = 0; jj < 4; ++jj)
          acc[i][jj] = __builtin_fmaf(av[i], bv[jj], acc[i][jj]);
    }
    __syncthreads();
  }

  float4 bv4;
  if (bias) bv4 = *(const float4*)(bias + bn + tn);
  else bv4 = make_float4(0.f, 0.f, 0.f, 0.f);
#pragma unroll
  for (int i = 0; i < 4; ++i) {
    int row = bm + tm + i;
    if (row < M) {
      float4 v;
      v.x = acc[i][0] + bv4.x;
      v.y = acc[i][1] + bv4.y;
      v.z = acc[i][2] + bv4.z;
      v.w = acc[i][3] + bv4.w;
      *(float4*)(C + (size_t)row * N + bn + tn) = v;
    }
  }
}

// ---------------- GCN edge aggregation (atomic scatter) ----------------
__global__ __launch_bounds__(256)
void k_aggregate(const float* __restrict__ xw, const void* __restrict__ edges,
                 const int* __restrict__ flag, const float* __restrict__ dinv,
                 float* __restrict__ out, int E) {
  int e = blockIdx.x * 8 + (threadIdx.x >> 5);
  if (e >= E) return;
  int i64 = *flag;
  int s = eidx(edges, i64, e);
  int d = eidx(edges, i64, (size_t)E + e);
  float nrm = dinv[s] * dinv[d];
  int f4 = threadIdx.x & 31;
  float4 v = ((const float4*)xw)[(size_t)s * 32 + f4];
  float* op = out + (size_t)d * 128 + f4 * 4;
  unsafeAtomicAdd(op + 0, v.x * nrm);
  unsafeAtomicAdd(op + 1, v.y * nrm);
  unsafeAtomicAdd(op + 2, v.z * nrm);
  unsafeAtomicAdd(op + 3, v.w * nrm);
}

__global__ void k_finish(float* __restrict__ h, const float* __restrict__ xw,
                         const float* __restrict__ dinv, const float* __restrict__ b,
                         int N) {
  int i4 = blockIdx.x * blockDim.x + threadIdx.x;
  if (i4 >= N * 32) return;
  int n = i4 >> 5;
  int f4 = (i4 & 31) << 2;
  float di = dinv[n];
  float s = di * di;
  float4 ag = ((const float4*)h)[i4];
  float4 xv = ((const float4*)xw)[i4];
  float4 bv = *(const float4*)(b + f4);
  float4 r;
  r.x = fmaxf(__builtin_fmaf(xv.x, s, ag.x) + bv.x, 0.f);
  r.y = fmaxf(__builtin_fmaf(xv.y, s, ag.y) + bv.y, 0.f);
  r.z = fmaxf(__builtin_fmaf(xv.z, s, ag.z) + bv.z, 0.f);
  r.w = fmaxf(__builtin_fmaf(xv.w, s, ag.w) + bv.w, 0.f);
  ((float4*)h)[i4] = r;
}

// ---------------- sequential LSTM scan: WHOLE LOOP IN ONE ASM BLOCK -------
// R14/R15 both failed with BIT-IDENTICAL absmax 2.502441e-03 -> the shared
// assumption was wrong: row_ror direction. Evidence says row_ror:4 delivers
// dest[i] = src[(i-4)&15] (not i+4). Under that convention:
//   v94 (ror:4)  = src[i-4]
//   v95 (ror:12) = src[i+4]
// Even-bank lanes (t&4==0, mb4 set) need src[i+4] -> must take v95.
// R16 = R15 with the single cndmask operand-order swap:
//   v_cndmask_b32 v94, v94, v95, mb4   (mask set -> v95)
// Everything else byte-identical to R15 (whose skeleton = passing R13).

#define DS_READS(ADR) \
  "ds_read_b128 v[96:99], %[" ADR "]\n\t" \
  "ds_read_b128 v[100:103], %[" ADR "] offset:16\n\t" \
  "ds_read_b128 v[104:107], %[" ADR "] offset:32\n\t" \
  "ds_read_b128 v[108:111], %[" ADR "] offset:48\n\t"

#define FMACORE \
  "s_waitcnt lgkmcnt(3)\n\t" \
  "v_pk_mul_f32 v[64:65], v[128:129], v[96:97]\n\t" \
  "v_pk_mul_f32 v[66:67], v[144:145], v[96:97]\n\t" \
  "v_pk_mul_f32 v[68:69], v[160:161], v[96:97]\n\t" \
  "v_pk_mul_f32 v[70:71], v[176:177], v[96:97]\n\t" \
  "v_pk_mul_f32 v[72:73], v[192:193], v[96:97]\n\t" \
  "v_pk_mul_f32 v[74:75], v[208:209], v[96:97]\n\t" \
  "v_pk_mul_f32 v[76:77], v[224:225], v[96:97]\n\t" \
  "v_pk_mul_f32 v[78:79], v[240:241], v[96:97]\n\t" \
  "v_pk_fma_f32 v[64:65], v[130:131], v[98:99], v[64:65]\n\t" \
  "v_pk_fma_f32 v[66:67], v[146:147], v[98:99], v[66:67]\n\t" \
  "v_pk_fma_f32 v[68:69], v[162:163], v[98:99], v[68:69]\n\t" \
  "v_pk_fma_f32 v[70:71], v[178:179], v[98:99], v[70:71]\n\t" \
  "v_pk_fma_f32 v[72:73], v[194:195], v[98:99], v[72:73]\n\t" \
  "v_pk_fma_f32 v[74:75], v[210:211], v[98:99], v[74:75]\n\t" \
  "v_pk_fma_f32 v[76:77], v[226:227], v[98:99], v[76:77]\n\t" \
  "v_pk_fma_f32 v[78:79], v[242:243], v[98:99], v[78:79]\n\t" \
  "s_waitcnt lgkmcnt(2)\n\t" \
  "v_pk_fma_f32 v[64:65], v[132:133], v[100:101], v[64:65]\n\t" \
  "v_pk_fma_f32 v[66:67], v[148:149], v[100:101], v[66:67]\n\t" \
  "v_pk_fma_f32 v[68:69], v[164:165], v[100:101], v[68:69]\n\t" \
  "v_pk_fma_f32 v[70:71], v[180:181], v[100:101], v[70:71]\n\t" \
  "v_pk_fma_f32 v[72:73], v[196:197], v[100:101], v[72:73]\n\t" \
  "v_pk_fma_f32 v[74:75], v[212:213], v[100:101], v[74:75]\n\t" \
  "v_pk_fma_f32 v[76:77], v[228:229], v[100:101], v[76:77]\n\t" \
  "v_pk_fma_f32 v[78:79], v[244:245], v[100:101], v[78:79]\n\t" \
  "v_pk_fma_f32 v[64:65], v[134:135], v[102:103], v[64:65]\n\t" \
  "v_pk_fma_f32 v[66:67], v[150:151], v[102:103], v[66:67]\n\t" \
  "v_pk_fma_f32 v[68:69], v[166:167], v[102:103], v[68:69]\n\t" \
  "v_pk_fma_f32 v[70:71], v[182:183], v[102:103], v[70:71]\n\t" \
  "v_pk_fma_f32 v[72:73], v[198:199], v[102:103], v[72:73]\n\t" \
  "v_pk_fma_f32 v[74:75], v[214:215], v[102:103], v[74:75]\n\t" \
  "v_pk_fma_f32 v[76:77], v[230:231], v[102:103], v[76:77]\n\t" \
  "v_pk_fma_f32 v[78:79], v[246:247], v[102:103], v[78:79]\n\t" \
  "s_waitcnt lgkmcnt(1)\n\t" \
  "v_pk_fma_f32 v[64:65], v[136:137], v[104:105], v[64:65]\n\t" \
  "v_pk_fma_f32 v[66:67], v[152:153], v[104:105], v[66:67]\n\t" \
  "v_pk_fma_f32 v[68:69], v[168:169], v[104:105], v[68:69]\n\t" \
  "v_pk_fma_f32 v[70:71], v[184:185], v[104:105], v[70:71]\n\t" \
  "v_pk_fma_f32 v[72:73], v[200:201], v[104:105], v[72:73]\n\t" \
  "v_pk_fma_f32 v[74:75], v[216:217], v[104:105], v[74:75]\n\t" \
  "v_pk_fma_f32 v[76:77], v[232:233], v[104:105], v[76:77]\n\t" \
  "v_pk_fma_f32 v[78:79], v[248:249], v[104:105], v[78:79]\n\t" \
  "v_pk_fma_f32 v[64:65], v[138:139], v[106:107], v[64:65]\n\t" \
  "v_pk_fma_f32 v[66:67], v[154:155], v[106:107], v[66:67]\n\t" \
  "v_pk_fma_f32 v[68:69], v[170:171], v[106:107], v[68:69]\n\t" \
  "v_pk_fma_f32 v[70:71], v[186:187], v[106:107], v[70:71]\n\t" \
  "v_pk_fma_f32 v[72:73], v[202:203], v[106:107], v[72:73]\n\t" \
  "v_pk_fma_f32 v[74:75], v[218:219], v[106:107], v[74:75]\n\t" \
  "v_pk_fma_f32 v[76:77], v[234:235], v[106:107], v[76:77]\n\t" \
  "v_pk_fma_f32 v[78:79], v[250:251], v[106:107], v[78:79]\n\t" \
  "s_waitcnt lgkmcnt(0)\n\t" \
  "v_pk_fma_f32 v[64:65], v[140:141], v[108:109], v[64:65]\n\t" \
  "v_pk_fma_f32 v[66:67], v[156:157], v[108:109], v[66:67]\n\t" \
  "v_pk_fma_f32 v[68:69], v[172:173], v[108:109], v[68:69]\n\t" \
  "v_pk_fma_f32 v[70:71], v[188:189], v[108:109], v[70:71]\n\t" \
  "v_pk_fma_f32 v[72:73], v[204:205], v[108:109], v[72:73]\n\t" \
  "v_pk_fma_f32 v[74:75], v[220:221], v[108:109], v[74:75]\n\t" \
  "v_pk_fma_f32 v[76:77], v[236:237], v[108:109], v[76:77]\n\t" \
  "v_pk_fma_f32 v[78:79], v[252:253], v[108:109], v[78:79]\n\t" \
  "v_pk_fma_f32 v[64:65], v[142:143], v[110:111], v[64:65]\n\t" \
  "v_pk_fma_f32 v[66:67], v[158:159], v[110:111], v[66:67]\n\t" \
  "v_pk_fma_f32 v[68:69], v[174:175], v[110:111], v[68:69]\n\t" \
  "v_pk_fma_f32 v[70:71], v[190:191], v[110:111], v[70:71]\n\t" \
  "v_pk_fma_f32 v[72:73], v[206:207], v[110:111], v[72:73]\n\t" \
  "v_pk_fma_f32 v[74:75], v[222:223], v[110:111], v[74:75]\n\t" \
  "v_pk_fma_f32 v[76:77], v[238:239], v[110:111], v[76:77]\n\t" \
  "v_pk_fma_f32 v[78:79], v[254:255], v[110:111], v[78:79]\n\t"

// collapse + select-free butterfly, all-VALU (no LDS on the chain).
// lane^4: two FULL-mask row_ror movs + cndmask on mb4, CORRECTED operand
// order per R14/R15 evidence (ror:4 -> src[i-4], ror:12 -> src[i+4];
// mb4-set lanes take v95 = src[i+4]).
// vmcnt(1): with {L_old,S,L_new,S} outstanding, >=3 retired must include
// the oldest load (loads retire in order) -> 2-step-old load complete.
#define REDUCE_FIXED \
  "v_add_f32 v80, v64, v65\n\t" \
  "v_add_f32 v81, v66, v67\n\t" \
  "v_add_f32 v82, v68, v69\n\t" \
  "v_add_f32 v83, v70, v71\n\t" \
  "v_add_f32 v84, v72, v73\n\t" \
  "v_add_f32 v85, v74, v75\n\t" \
  "v_add_f32 v86, v76, v77\n\t" \
  "v_add_f32 v87, v78, v79\n\t" \
  "v_add_f32 v88, v81, v80 quad_perm:[1,0,3,2] row_mask:0xf bank_mask:0xf\n\t" \
  "v_add_f32 v89, v83, v82 quad_perm:[1,0,3,2] row_mask:0xf bank_mask:0xf\n\t" \
  "v_add_f32 v90, v85, v84 quad_perm:[1,0,3,2] row_mask:0xf bank_mask:0xf\n\t" \
  "v_add_f32 v91, v87, v86 quad_perm:[1,0,3,2] row_mask:0xf bank_mask:0xf\n\t" \
  "v_add_f32 v92, v89, v88 quad_perm:[2,3,0,1] row_mask:0xf bank_mask:0xf\n\t" \
  "s_nop 0\n\t" \
  "v_add_f32 v93, v91, v90 quad_perm:[2,3,0,1] row_mask:0xf bank_mask:0xf\n\t" \
  "s_nop 1\n\t" \
  "v_mov_b32 v94, v93 row_ror:4 row_mask:0xf bank_mask:0xf\n\t" \
  "v_mov_b32 v95, v93 row_ror:12 row_mask:0xf bank_mask:0xf\n\t" \
  "s_nop 0\n\t" \
  "v_cndmask_b32 v94, v94, v95, %[mb4]\n\t" \
  "s_waitcnt vmcnt(1)\n\t"

#define GLOAD(GX) \
  "v_add_f32 v92, v92, %[" GX "]\n\t" \
  "v_add_f32 v92, v92, v94\n\t" \
  "global_load_dword %[" GX "], %[gio], %[gin]\n\t" \
  "v_add_u32 %[gio], 0x800, %[gio]\n\t"

// activation (per-lane consts) + gate combine via DPP products + c/h update
#define ACT_CH \
  "v_mul_f32 v80, %[kexp], v92\n\t" \
  "v_exp_f32 v80, v80\n\t" \
  "s_nop 1\n\t" \
  "v_add_f32 v80, 1.0, v80\n\t" \
  "v_rcp_f32 v80, v80\n\t" \
  "s_nop 1\n\t" \
  "v_fma_f32 v81, v80, %[sA], %[sB]\n\t" \
  "s_nop 1\n\t" \
  "v_mul_f32 v82, v81, v81 quad_perm:[2,3,0,1] row_mask:0xf bank_mask:0xf\n\t" \
  "v_mov_b32 v83, v81 quad_perm:[1,1,1,1] row_mask:0xf bank_mask:0xf\n\t" \
  "v_mov_b32 v84, v81 quad_perm:[3,3,3,3] row_mask:0xf bank_mask:0xf\n\t" \
  "v_mov_b32 v85, v82 quad_perm:[1,0,3,2] row_mask:0xf bank_mask:0xf\n\t" \
  "s_nop 0\n\t" \
  "v_cndmask_b32 v85, v82, v85, %[modd]\n\t" \
  "v_fma_f32 %[cc], v83, %[cc], v85\n\t" \
  "v_mul_f32 v86, 0x4038aa3b, %[cc]\n\t" \
  "v_exp_f32 v86, v86\n\t" \
  "s_nop 1\n\t" \
  "v_add_f32 v86, 1.0, v86\n\t" \
  "v_rcp_f32 v86, v86\n\t" \
  "s_nop 1\n\t" \
  "v_mul_f32 v87, v84, v86\n\t" \
  "v_fma_f32 v87, -2.0, v87, v84\n\t"

#define HSTORE(WW) \
  "s_mov_b64 exec, %[m0q]\n\t" \
  "ds_write_b32 %[" WW "], v87\n\t" \
  "global_store_dword %[hso], v87, %[hsb]\n\t" \
  "s_mov_b64 exec, -1\n\t" \
  "v_add_u32 %[hso], 0x200, %[hso]\n\t" \
  "s_waitcnt lgkmcnt(0)\n\t" \
  "s_barrier\n\t"

__global__ __launch_bounds__(512)
__attribute__((amdgpu_waves_per_eu(2, 2)))
void k_lstm(const float* __restrict__ g_in, const float* __restrict__ wp,
            float* __restrict__ hs, int T) {
  const int t = threadIdx.x;
  const int j = t & 7;
  const int g8 = t >> 3;
  const int pos = t & 3;               // gate: 0=i 1=f 2=g 3=o
  const int du = (t >> 2) & 1;
  const int unit = 2 * g8 + du;
  const int row = pos * 128 + unit;
  const bool isg = (pos == 2);

  __shared__ __align__(16) float hbuf[2][160];
  __shared__ float lds_cap[20736];     // 82944 B occupancy anchor

  if (t == 0) {
    volatile float* vp = lds_cap;
    vp[0] = 0.f;
  }
  if (t < 160) { hbuf[0][t] = 0.f; hbuf[1][t] = 0.f; }

  // ---- ALL setup BEFORE the preload asm ----
  uint32_t ar0 = (uint32_t)(uintptr_t)&hbuf[0][20 * j];
  uint32_t ar1 = (uint32_t)(uintptr_t)&hbuf[1][20 * j];
  uint32_t w0  = (uint32_t)(uintptr_t)&hbuf[0][20 * (unit >> 4) + (unit & 15)];
  uint32_t w1  = (uint32_t)(uintptr_t)&hbuf[1][20 * (unit >> 4) + (unit & 15)];
  uint32_t gio = (uint32_t)(row * 4);
  uint32_t hso = (uint32_t)(unit * 4);
  float kexp = isg ? -2.8853900817779268f : -1.4426950408889634f;
  float sA   = isg ? 2.f : 1.f;
  float sB   = isg ? -1.f : 0.f;
  unsigned long long m0q  = __ballot(pos == 0);
  unsigned long long modd = __ballot((pos & 1) != 0);
  unsigned long long mb4  = __ballot((t & 4) == 0);   // even banks: need src[i+4]
  float cc = 0.f, ga = 0.f, gb = 0.f;
  int cnt = T >> 1;                     // T is even (20000)
  const float* wr = wp + (size_t)t * 128;

  // -------- one-time weight preload into physical v128..v255 --------
  asm volatile(
    "global_load_dwordx4 v[128:131], %0, off\n\t"
    "global_load_dwordx4 v[132:135], %0, off offset:16\n\t"
    "global_load_dwordx4 v[136:139], %0, off offset:32\n\t"
    "global_load_dwordx4 v[140:143], %0, off offset:48\n\t"
    "global_load_dwordx4 v[144:147], %0, off offset:64\n\t"
    "global_load_dwordx4 v[148:151], %0, off offset:80\n\t"
    "global_load_dwordx4 v[152:155], %0, off offset:96\n\t"
    "global_load_dwordx4 v[156:159], %0, off offset:112\n\t"
    "global_load_dwordx4 v[160:163], %0, off offset:128\n\t"
    "global_load_dwordx4 v[164:167], %0, off offset:144\n\t"
    "global_load_dwordx4 v[168:171], %0, off offset:160\n\t"
    "global_load_dwordx4 v[172:175], %0, off offset:176\n\t"
    "global_load_dwordx4 v[176:179], %0, off offset:192\n\t"
    "global_load_dwordx4 v[180:183], %0, off offset:208\n\t"
    "global_load_dwordx4 v[184:187], %0, off offset:224\n\t"
    "global_load_dwordx4 v[188:191], %0, off offset:240\n\t"
    "global_load_dwordx4 v[192:195], %0, off offset:256\n\t"
    "global_load_dwordx4 v[196:199], %0, off offset:272\n\t"
    "global_load_dwordx4 v[200:203], %0, off offset:288\n\t"
    "global_load_dwordx4 v[204:207], %0, off offset:304\n\t"
    "global_load_dwordx4 v[208:211], %0, off offset:320\n\t"
    "global_load_dwordx4 v[212:215], %0, off offset:336\n\t"
    "global_load_dwordx4 v[216:219], %0, off offset:352\n\t"
    "global_load_dwordx4 v[220:223], %0, off offset:368\n\t"
    "global_load_dwordx4 v[224:227], %0, off offset:384\n\t"
    "global_load_dwordx4 v[228:231], %0, off offset:400\n\t"
    "global_load_dwordx4 v[232:235], %0, off offset:416\n\t"
    "global_load_dwordx4 v[236:239], %0, off offset:432\n\t"
    "global_load_dwordx4 v[240:243], %0, off offset:448\n\t"
    "global_load_dwordx4 v[244:247], %0, off offset:464\n\t"
    "global_load_dwordx4 v[248:251], %0, off offset:480\n\t"
    "global_load_dwordx4 v[252:255], %0, off offset:496\n\t"
    "s_waitcnt vmcnt(0)"
    :: "v"(wr)
    : "v128","v129","v130","v131","v132","v133","v134","v135",
      "v136","v137","v138","v139","v140","v141","v142","v143",
      "v144","v145","v146","v147","v148","v149","v150","v151",
      "v152","v153","v154","v155","v156","v157","v158","v159",
      "v160","v161","v162","v163","v164","v165","v166","v167",
      "v168","v169","v170","v171","v172","v173","v174","v175",
      "v176","v177","v178","v179","v180","v181","v182","v183",
      "v184","v185","v186","v187","v188","v189","v190","v191",
      "v192","v193","v194","v195","v196","v197","v198","v199",
      "v200","v201","v202","v203","v204","v205","v206","v207",
      "v208","v209","v210","v211","v212","v213","v214","v215",
      "v216","v217","v218","v219","v220","v221","v222","v223",
      "v224","v225","v226","v227","v228","v229","v230","v231",
      "v232","v233","v234","v235","v236","v237","v238","v239",
      "v240","v241","v242","v243","v244","v245","v246","v247",
      "v248","v249","v250","v251","v252","v253","v254","v255");

  __syncthreads();

  asm volatile(
    // prologue: load g rows for steps 0,1; advance gio to step 2
    "global_load_dword %[ga], %[gio], %[gin]\n\t"
    "v_add_u32 %[gio], 0x800, %[gio]\n\t"
    "global_load_dword %[gb], %[gio], %[gin]\n\t"
    "v_add_u32 %[gio], 0x800, %[gio]\n\t"
    "s_waitcnt vmcnt(0)\n\t"
    "Lscan%=:\n\t"
    // ---- half A: even step, read buf0, write buf1, uses ga ----
    DS_READS("ar0")
    FMACORE
    REDUCE_FIXED
    GLOAD("ga")
    ACT_CH
    HSTORE("w1")
    // ---- half B: odd step, read buf1, write buf0, uses gb ----
    DS_READS("ar1")
    FMACORE
    REDUCE_FIXED
    GLOAD("gb")
    ACT_CH
    HSTORE("w0")
    // loop control
    "s_sub_u32 %[cnt], %[cnt], 1\n\t"
    "s_cmp_lg_u32 %[cnt], 0\n\t"
    "s_cbranch_scc1 Lscan%=\n\t"
    : [cc]"=&v"(cc), [ga]"=&v"(ga), [gb]"=&v"(gb),
      [gio]"=&v"(gio), [hso]"=&v"(hso), [cnt]"=&s"(cnt)
    : [gin]"s"(g_in), [hsb]"s"(hs),
      [m0q]"s"(m0q), [modd]"s"(modd), [mb4]"s"(mb4),
      [ar0]"v"(ar0), [ar1]"v"(ar1), [w0]"v"(w0), [w1]"v"(w1),
      [kexp]"v"(kexp), [sA]"v"(sA), [sB]"v"(sB),
      "0"(cc), "1"(ga), "2"(gb), "3"(gio), "4"(hso), "5"(cnt)
    : "memory", "scc",
      "v64","v65","v66","v67","v68","v69","v70","v71",
      "v72","v73","v74","v75","v76","v77","v78","v79",
      "v80","v81","v82","v83","v84","v85","v86","v87",
      "v88","v89","v90","v91","v92","v93","v94","v95",
      "v96","v97","v98","v99","v100","v101","v102","v103",
      "v104","v105","v106","v107","v108","v109","v110","v111",
      "v128","v129","v130","v131","v132","v133","v134","v135",
      "v136","v137","v138","v139","v140","v141","v142","v143",
      "v144","v145","v146","v147","v148","v149","v150","v151",
      "v152","v153","v154","v155","v156","v157","v158","v159",
      "v160","v161","v162","v163","v164","v165","v166","v167",
      "v168","v169","v170","v171","v172","v173","v174","v175",
      "v176","v177","v178","v179","v180","v181","v182","v183",
      "v184","v185","v186","v187","v188","v189","v190","v191",
      "v192","v193","v194","v195","v196","v197","v198","v199",
      "v200","v201","v202","v203","v204","v205","v206","v207",
      "v208","v209","v210","v211","v212","v213","v214","v215",
      "v216","v217","v218","v219","v220","v221","v222","v223",
      "v224","v225","v226","v227","v228","v229","v230","v231",
      "v232","v233","v234","v235","v236","v237","v238","v239",
      "v240","v241","v242","v243","v244","v245","v246","v247",
      "v248","v249","v250","v251","v252","v253","v254","v255");
}

// ---------------- host launch ----------------

extern "C" void kernel_launch(void* const* d_in, const int* in_sizes, int n_in,
                              void* d_out, int out_size, void* d_ws, size_t ws_size,
                              hipStream_t stream) {
  const float* x     = (const float*)d_in[0];
  const void* edges  = d_in[1];
  const float* W1    = (const float*)d_in[2];
  const float* b1    = (const float*)d_in[3];
  const float* W2    = (const float*)d_in[4];
  const float* b2    = (const float*)d_in[5];
  const float* W_ih  = (const float*)d_in[6];
  const float* W_hh  = (const float*)d_in[7];
  const float* b_ih  = (const float*)d_in[8];
  const float* b_hh  = (const float*)d_in[9];
  const float* W_lin = (const float*)d_in[10];
  const float* b_lin = (const float*)d_in[11];
  float* out = (float*)d_out;

  const int N = in_sizes[0] / NF;  // 20000
  const int E = in_sizes[1] / 2;   // 640000
  const int OUTF = 64;

  char* base = (char*)d_ws;
  size_t off = 0;
  auto alloc = [&](size_t b) {
    char* p = base + off;
    off += (b + 255) & ~(size_t)255;
    return p;
  };
  float* dinv = (float*)alloc((size_t)N * 4);
  float* W1T  = (float*)alloc(128 * 128 * 4);
  float* W2T  = (float*)alloc(128 * 128 * 4);
  float* wp   = (float*)alloc(512 * 128 * 4);
  float* bsum = (float*)alloc(512 * 4);
  int*   flag = (int*)alloc(256);
  float* bufA = (float*)alloc((size_t)N * NF * 4);
  float* bufB = (float*)alloc((size_t)N * NF * 4);
  float* bufC = (float*)alloc((size_t)N * NF * 4);
  float* g_in = (float*)alloc(((size_t)N + 4) * (size_t)G4 * 4);  // +4 rows slack (prefetch OOB)
  if (off > ws_size) return;

  k_fill<<<(N + 255) / 256, 256, 0, stream>>>(dinv, 1.0f, N);
  k_detect_i64<<<1, 1, 0, stream>>>((const int*)edges, 1024, flag);
  k_count<<<(E + 255) / 256, 256, 0, stream>>>(edges, flag, dinv, E);
  k_rsqrt<<<(N + 255) / 256, 256, 0, stream>>>(dinv, N);
  k_t128<<<128, 128, 0, stream>>>(W1, W1T);
  k_t128<<<128, 128, 0, stream>>>(W2, W2T);
  k_wprep<<<512, 128, 0, stream>>>(W_hh, wp);
  k_add<<<2, 256, 0, stream>>>(b_ih, b_hh, bsum, 512);

  const int mg = (N + 63) / 64;

  gemm_bt<<<dim3(mg, 2), 256, 0, stream>>>(x, W1T, nullptr, bufA, N, NF, NF);
  hipMemsetAsync(bufB, 0, (size_t)N * NF * 4, stream);
  k_aggregate<<<(E + 7) / 8, 256, 0, stream>>>(bufA, edges, flag, dinv, bufB, E);
  k_finish<<<(N * 32 + 255) / 256, 256, 0, stream>>>(bufB, bufA, dinv, b1, N);

  gemm_bt<<<dim3(mg, 2), 256, 0, stream>>>(bufB, W2T, nullptr, bufA, N, NF, NF);
  hipMemsetAsync(bufC, 0, (size_t)N * NF * 4, stream);
  k_aggregate<<<(E + 7) / 8, 256, 0, stream>>>(bufA, edges, flag, dinv, bufC, E);
  k_finish<<<(N * 32 + 255) / 256, 256, 0, stream>>>(bufC, bufA, dinv, b2, N);

  gemm_bt<<<dim3(mg, 8), 256, 0, stream>>>(bufC, W_ih, bsum, g_in, N, G4, NF);

  k_lstm<<<1, 512, 0, stream>>>(g_in, wp, bufB, N);

  gemm_bt<<<dim3(mg, 1), 256, 0, stream>>>(bufB, W_lin, b_lin, out, N, OUTF, NF);
}

// Round 18
// 12213.273 us; speedup vs baseline: 1.2271x; 1.0040x over previous
//
#include <hip/hip_runtime.h>
#include <cstdint>

#define NF 128   // node feature / hidden width
#define G4 512   // 4*H gates

// ---------------- small utility kernels ----------------

__global__ void k_fill(float* p, float v, int n) {
  int i = blockIdx.x * blockDim.x + threadIdx.x;
  if (i < n) p[i] = v;
}

__global__ void k_detect_i64(const int* e, int npairs, int* flag) {
  int f = 1;
  for (int i = 1; i < 2 * npairs; i += 2)
    if (e[i] != 0) { f = 0; break; }
  *flag = f;
}

__device__ __forceinline__ int eidx(const void* edges, int i64, size_t pos) {
  if (i64) return (int)((const long long*)edges)[pos];
  return ((const int*)edges)[pos];
}

__global__ void k_count(const void* __restrict__ edges, const int* __restrict__ flag,
                        float* __restrict__ deg, int E) {
  int e = blockIdx.x * blockDim.x + threadIdx.x;
  if (e < E) {
    int d = eidx(edges, *flag, (size_t)E + e);
    unsafeAtomicAdd(&deg[d], 1.0f);
  }
}

__global__ void k_rsqrt(float* p, int n) {
  int i = blockIdx.x * blockDim.x + threadIdx.x;
  if (i < n) p[i] = rsqrtf(p[i]);
}

__global__ void k_t128(const float* __restrict__ in, float* __restrict__ out) {
  int n = blockIdx.x, k = threadIdx.x;
  out[n * 128 + k] = in[k * 128 + n];
}

__global__ void k_add(const float* a, const float* b, float* o, int n) {
  int i = blockIdx.x * blockDim.x + threadIdx.x;
  if (i < n) o[i] = a[i] + b[i];
}

// Weight prep for the 8-lane-group LSTM layout (verified R9-R16).
__global__ void k_wprep(const float* __restrict__ W, float* __restrict__ wp) {
  int t = blockIdx.x;        // 0..511
  int m = threadIdx.x;       // 0..127
  int j = t & 7;
  int g8 = t >> 3;
  int blk = m >> 4;          // chain index 0..7
  int k = m & 15;
  int rr = j ^ blk;          // row within group
  int gate = rr & 3, du = rr >> 2;
  int unit = 2 * g8 + du;
  int col = 16 * j + k;
  wp[(size_t)t * 128 + m] = W[(size_t)(gate * 128 + unit) * 128 + col];
}

// ---------------- GEMM: C[M,N] = A[M,K] @ B[N,K]^T (+bias) ----------------
__global__ __launch_bounds__(256)
void gemm_bt(const float* __restrict__ A, const float* __restrict__ B,
             const float* __restrict__ bias, float* __restrict__ C,
             int M, int N, int K) {
  __shared__ float As[32][68];
  __shared__ float Bs[32][68];
  const int bm = blockIdx.x * 64;
  const int bn = blockIdx.y * 64;
  const int tid = threadIdx.x;
  const int tm = (tid & 15) << 2;
  const int tn = (tid >> 4) << 2;
  float acc[4][4] = {};

  for (int k0 = 0; k0 < K; k0 += 32) {
#pragma unroll
    for (int l = 0; l < 2; ++l) {
      int idx = tid + l * 256;
      int row = idx >> 3;
      int k4 = (idx & 7) << 2;
      int ar = bm + row; ar = ar < M ? ar : M - 1;
      float4 av = *(const float4*)(A + (size_t)ar * K + k0 + k4);
      As[k4 + 0][row] = av.x; As[k4 + 1][row] = av.y;
      As[k4 + 2][row] = av.z; As[k4 + 3][row] = av.w;
      int br = bn + row; br = br < N ? br : N - 1;
      float4 bv = *(const float4*)(B + (size_t)br * K + k0 + k4);
      Bs[k4 + 0][row] = bv.x; Bs[k4 + 1][row] = bv.y;
      Bs[k4 + 2][row] = bv.z; Bs[k4 + 3][row] = bv.w;
    }
    __syncthreads();
#pragma unroll
    for (int kk = 0; kk < 32; ++kk) {
      float4 a = *(const float4*)&As[kk][tm];
      float4 b = *(const float4*)&Bs[kk][tn];
      float av[4] = {a.x, a.y, a.z, a.w};
      float bv[4] = {b.x, b.y, b.z, b.w};
#pragma unroll
      for (int i = 0; i < 4; ++i)
#pragma unroll
        for (int jj = 0; jj < 4; ++jj)
          acc[i][jj] = __builtin_fmaf(av[i], bv[jj], acc[i][jj]);
    }
    __syncthreads();
  }

  float4 bv4;
  if (bias) bv4 = *(const float4*)(bias + bn + tn);
  else bv4 = make_float4(0.f, 0.f, 0.f, 0.f);
#pragma unroll
  for (int i = 0; i < 4; ++i) {
    int row = bm + tm + i;
    if (row < M) {
      float4 v;
      v.x = acc[i][0] + bv4.x;
      v.y = acc[i][1] + bv4.y;
      v.z = acc[i][2] + bv4.z;
      v.w = acc[i][3] + bv4.w;
      *(float4*)(C + (size_t)row * N + bn + tn) = v;
    }
  }
}

// ---------------- GCN edge aggregation (atomic scatter) ----------------
__global__ __launch_bounds__(256)
void k_aggregate(const float* __restrict__ xw, const void* __restrict__ edges,
                 const int* __restrict__ flag, const float* __restrict__ dinv,
                 float* __restrict__ out, int E) {
  int e = blockIdx.x * 8 + (threadIdx.x >> 5);
  if (e >= E) return;
  int i64 = *flag;
  int s = eidx(edges, i64, e);
  int d = eidx(edges, i64, (size_t)E + e);
  float nrm = dinv[s] * dinv[d];
  int f4 = threadIdx.x & 31;
  float4 v = ((const float4*)xw)[(size_t)s * 32 + f4];
  float* op = out + (size_t)d * 128 + f4 * 4;
  unsafeAtomicAdd(op + 0, v.x * nrm);
  unsafeAtomicAdd(op + 1, v.y * nrm);
  unsafeAtomicAdd(op + 2, v.z * nrm);
  unsafeAtomicAdd(op + 3, v.w * nrm);
}

__global__ void k_finish(float* __restrict__ h, const float* __restrict__ xw,
                         const float* __restrict__ dinv, const float* __restrict__ b,
                         int N) {
  int i4 = blockIdx.x * blockDim.x + threadIdx.x;
  if (i4 >= N * 32) return;
  int n = i4 >> 5;
  int f4 = (i4 & 31) << 2;
  float di = dinv[n];
  float s = di * di;
  float4 ag = ((const float4*)h)[i4];
  float4 xv = ((const float4*)xw)[i4];
  float4 bv = *(const float4*)(b + f4);
  float4 r;
  r.x = fmaxf(__builtin_fmaf(xv.x, s, ag.x) + bv.x, 0.f);
  r.y = fmaxf(__builtin_fmaf(xv.y, s, ag.y) + bv.y, 0.f);
  r.z = fmaxf(__builtin_fmaf(xv.z, s, ag.z) + bv.z, 0.f);
  r.w = fmaxf(__builtin_fmaf(xv.w, s, ag.w) + bv.w, 0.f);
  ((float4*)h)[i4] = r;
}

// ---------------- sequential LSTM scan: WHOLE LOOP IN ONE ASM BLOCK -------
// R17 NaN root cause: removed trans-op s_nops. Inside an asm block the
// backend's hazard recognizer cannot insert the required VALU-trans ->
// consumer wait states (outside asm it does so invisibly, which is why
// compiler-generated exp/rcp code shows none). R18 = R17's SAFE half:
// keep the audited offset folding (GLOAD_A/B, HSTORE_A/B), restore ALL
// trans-op s_nops (ACT_CH byte-identical to passing R16).

#define DS_READS(ADR) \
  "ds_read_b128 v[96:99], %[" ADR "]\n\t" \
  "ds_read_b128 v[100:103], %[" ADR "] offset:16\n\t" \
  "ds_read_b128 v[104:107], %[" ADR "] offset:32\n\t" \
  "ds_read_b128 v[108:111], %[" ADR "] offset:48\n\t"

#define FMACORE \
  "s_waitcnt lgkmcnt(3)\n\t" \
  "v_pk_mul_f32 v[64:65], v[128:129], v[96:97]\n\t" \
  "v_pk_mul_f32 v[66:67], v[144:145], v[96:97]\n\t" \
  "v_pk_mul_f32 v[68:69], v[160:161], v[96:97]\n\t" \
  "v_pk_mul_f32 v[70:71], v[176:177], v[96:97]\n\t" \
  "v_pk_mul_f32 v[72:73], v[192:193], v[96:97]\n\t" \
  "v_pk_mul_f32 v[74:75], v[208:209], v[96:97]\n\t" \
  "v_pk_mul_f32 v[76:77], v[224:225], v[96:97]\n\t" \
  "v_pk_mul_f32 v[78:79], v[240:241], v[96:97]\n\t" \
  "v_pk_fma_f32 v[64:65], v[130:131], v[98:99], v[64:65]\n\t" \
  "v_pk_fma_f32 v[66:67], v[146:147], v[98:99], v[66:67]\n\t" \
  "v_pk_fma_f32 v[68:69], v[162:163], v[98:99], v[68:69]\n\t" \
  "v_pk_fma_f32 v[70:71], v[178:179], v[98:99], v[70:71]\n\t" \
  "v_pk_fma_f32 v[72:73], v[194:195], v[98:99], v[72:73]\n\t" \
  "v_pk_fma_f32 v[74:75], v[210:211], v[98:99], v[74:75]\n\t" \
  "v_pk_fma_f32 v[76:77], v[226:227], v[98:99], v[76:77]\n\t" \
  "v_pk_fma_f32 v[78:79], v[242:243], v[98:99], v[78:79]\n\t" \
  "s_waitcnt lgkmcnt(2)\n\t" \
  "v_pk_fma_f32 v[64:65], v[132:133], v[100:101], v[64:65]\n\t" \
  "v_pk_fma_f32 v[66:67], v[148:149], v[100:101], v[66:67]\n\t" \
  "v_pk_fma_f32 v[68:69], v[164:165], v[100:101], v[68:69]\n\t" \
  "v_pk_fma_f32 v[70:71], v[180:181], v[100:101], v[70:71]\n\t" \
  "v_pk_fma_f32 v[72:73], v[196:197], v[100:101], v[72:73]\n\t" \
  "v_pk_fma_f32 v[74:75], v[212:213], v[100:101], v[74:75]\n\t" \
  "v_pk_fma_f32 v[76:77], v[228:229], v[100:101], v[76:77]\n\t" \
  "v_pk_fma_f32 v[78:79], v[244:245], v[100:101], v[78:79]\n\t" \
  "v_pk_fma_f32 v[64:65], v[134:135], v[102:103], v[64:65]\n\t" \
  "v_pk_fma_f32 v[66:67], v[150:151], v[102:103], v[66:67]\n\t" \
  "v_pk_fma_f32 v[68:69], v[166:167], v[102:103], v[68:69]\n\t" \
  "v_pk_fma_f32 v[70:71], v[182:183], v[102:103], v[70:71]\n\t" \
  "v_pk_fma_f32 v[72:73], v[198:199], v[102:103], v[72:73]\n\t" \
  "v_pk_fma_f32 v[74:75], v[214:215], v[102:103], v[74:75]\n\t" \
  "v_pk_fma_f32 v[76:77], v[230:231], v[102:103], v[76:77]\n\t" \
  "v_pk_fma_f32 v[78:79], v[246:247], v[102:103], v[78:79]\n\t" \
  "s_waitcnt lgkmcnt(1)\n\t" \
  "v_pk_fma_f32 v[64:65], v[136:137], v[104:105], v[64:65]\n\t" \
  "v_pk_fma_f32 v[66:67], v[152:153], v[104:105], v[66:67]\n\t" \
  "v_pk_fma_f32 v[68:69], v[168:169], v[104:105], v[68:69]\n\t" \
  "v_pk_fma_f32 v[70:71], v[184:185], v[104:105], v[70:71]\n\t" \
  "v_pk_fma_f32 v[72:73], v[200:201], v[104:105], v[72:73]\n\t" \
  "v_pk_fma_f32 v[74:75], v[216:217], v[104:105], v[74:75]\n\t" \
  "v_pk_fma_f32 v[76:77], v[232:233], v[104:105], v[76:77]\n\t" \
  "v_pk_fma_f32 v[78:79], v[248:249], v[104:105], v[78:79]\n\t" \
  "v_pk_fma_f32 v[64:65], v[138:139], v[106:107], v[64:65]\n\t" \
  "v_pk_fma_f32 v[66:67], v[154:155], v[106:107], v[66:67]\n\t" \
  "v_pk_fma_f32 v[68:69], v[170:171], v[106:107], v[68:69]\n\t" \
  "v_pk_fma_f32 v[70:71], v[186:187], v[106:107], v[70:71]\n\t" \
  "v_pk_fma_f32 v[72:73], v[202:203], v[106:107], v[72:73]\n\t" \
  "v_pk_fma_f32 v[74:75], v[218:219], v[106:107], v[74:75]\n\t" \
  "v_pk_fma_f32 v[76:77], v[234:235], v[106:107], v[76:77]\n\t" \
  "v_pk_fma_f32 v[78:79], v[250:251], v[106:107], v[78:79]\n\t" \
  "s_waitcnt lgkmcnt(0)\n\t" \
  "v_pk_fma_f32 v[64:65], v[140:141], v[108:109], v[64:65]\n\t" \
  "v_pk_fma_f32 v[66:67], v[156:157], v[108:109], v[66:67]\n\t" \
  "v_pk_fma_f32 v[68:69], v[172:173], v[108:109], v[68:69]\n\t" \
  "v_pk_fma_f32 v[70:71], v[188:189], v[108:109], v[70:71]\n\t" \
  "v_pk_fma_f32 v[72:73], v[204:205], v[108:109], v[72:73]\n\t" \
  "v_pk_fma_f32 v[74:75], v[220:221], v[108:109], v[74:75]\n\t" \
  "v_pk_fma_f32 v[76:77], v[236:237], v[108:109], v[76:77]\n\t" \
  "v_pk_fma_f32 v[78:79], v[252:253], v[108:109], v[78:79]\n\t" \
  "v_pk_fma_f32 v[64:65], v[142:143], v[110:111], v[64:65]\n\t" \
  "v_pk_fma_f32 v[66:67], v[158:159], v[110:111], v[66:67]\n\t" \
  "v_pk_fma_f32 v[68:69], v[174:175], v[110:111], v[68:69]\n\t" \
  "v_pk_fma_f32 v[70:71], v[190:191], v[110:111], v[70:71]\n\t" \
  "v_pk_fma_f32 v[72:73], v[206:207], v[110:111], v[72:73]\n\t" \
  "v_pk_fma_f32 v[74:75], v[222:223], v[110:111], v[74:75]\n\t" \
  "v_pk_fma_f32 v[76:77], v[238:239], v[110:111], v[76:77]\n\t" \
  "v_pk_fma_f32 v[78:79], v[254:255], v[110:111], v[78:79]\n\t"

// collapse + select-free butterfly, all-VALU (R16-verified).
#define REDUCE_FIXED \
  "v_add_f32 v80, v64, v65\n\t" \
  "v_add_f32 v81, v66, v67\n\t" \
  "v_add_f32 v82, v68, v69\n\t" \
  "v_add_f32 v83, v70, v71\n\t" \
  "v_add_f32 v84, v72, v73\n\t" \
  "v_add_f32 v85, v74, v75\n\t" \
  "v_add_f32 v86, v76, v77\n\t" \
  "v_add_f32 v87, v78, v79\n\t" \
  "v_add_f32 v88, v81, v80 quad_perm:[1,0,3,2] row_mask:0xf bank_mask:0xf\n\t" \
  "v_add_f32 v89, v83, v82 quad_perm:[1,0,3,2] row_mask:0xf bank_mask:0xf\n\t" \
  "v_add_f32 v90, v85, v84 quad_perm:[1,0,3,2] row_mask:0xf bank_mask:0xf\n\t" \
  "v_add_f32 v91, v87, v86 quad_perm:[1,0,3,2] row_mask:0xf bank_mask:0xf\n\t" \
  "v_add_f32 v92, v89, v88 quad_perm:[2,3,0,1] row_mask:0xf bank_mask:0xf\n\t" \
  "s_nop 0\n\t" \
  "v_add_f32 v93, v91, v90 quad_perm:[2,3,0,1] row_mask:0xf bank_mask:0xf\n\t" \
  "s_nop 1\n\t" \
  "v_mov_b32 v94, v93 row_ror:4 row_mask:0xf bank_mask:0xf\n\t" \
  "v_mov_b32 v95, v93 row_ror:12 row_mask:0xf bank_mask:0xf\n\t" \
  "s_nop 0\n\t" \
  "v_cndmask_b32 v94, v94, v95, %[mb4]\n\t" \
  "s_waitcnt vmcnt(1)\n\t"

// half A: load for step n+2 at gio (no advance)
#define GLOAD_A(GX) \
  "v_add_f32 v92, v92, %[" GX "]\n\t" \
  "v_add_f32 v92, v92, v94\n\t" \
  "global_load_dword %[" GX "], %[gio], %[gin]\n\t"

// half B: load for step n+3 at gio+0x800, then advance one iteration
#define GLOAD_B(GX) \
  "v_add_f32 v92, v92, %[" GX "]\n\t" \
  "v_add_f32 v92, v92, v94\n\t" \
  "global_load_dword %[" GX "], %[gio], %[gin] offset:0x800\n\t" \
  "v_add_u32 %[gio], 0x1000, %[gio]\n\t"

// activation + gate combine + c/h update (byte-identical to passing R16:
// all trans-op s_nops present -- REQUIRED inside asm blocks)
#define ACT_CH \
  "v_mul_f32 v80, %[kexp], v92\n\t" \
  "v_exp_f32 v80, v80\n\t" \
  "s_nop 1\n\t" \
  "v_add_f32 v80, 1.0, v80\n\t" \
  "v_rcp_f32 v80, v80\n\t" \
  "s_nop 1\n\t" \
  "v_fma_f32 v81, v80, %[sA], %[sB]\n\t" \
  "s_nop 1\n\t" \
  "v_mul_f32 v82, v81, v81 quad_perm:[2,3,0,1] row_mask:0xf bank_mask:0xf\n\t" \
  "v_mov_b32 v83, v81 quad_perm:[1,1,1,1] row_mask:0xf bank_mask:0xf\n\t" \
  "v_mov_b32 v84, v81 quad_perm:[3,3,3,3] row_mask:0xf bank_mask:0xf\n\t" \
  "v_mov_b32 v85, v82 quad_perm:[1,0,3,2] row_mask:0xf bank_mask:0xf\n\t" \
  "s_nop 0\n\t" \
  "v_cndmask_b32 v85, v82, v85, %[modd]\n\t" \
  "v_fma_f32 %[cc], v83, %[cc], v85\n\t" \
  "v_mul_f32 v86, 0x4038aa3b, %[cc]\n\t" \
  "v_exp_f32 v86, v86\n\t" \
  "s_nop 1\n\t" \
  "v_add_f32 v86, 1.0, v86\n\t" \
  "v_rcp_f32 v86, v86\n\t" \
  "s_nop 1\n\t" \
  "v_mul_f32 v87, v84, v86\n\t" \
  "v_fma_f32 v87, -2.0, v87, v84\n\t"

// half A: store even step at hso (no advance)
#define HSTORE_A(WW) \
  "s_mov_b64 exec, %[m0q]\n\t" \
  "ds_write_b32 %[" WW "], v87\n\t" \
  "global_store_dword %[hso], v87, %[hsb]\n\t" \
  "s_mov_b64 exec, -1\n\t" \
  "s_waitcnt lgkmcnt(0)\n\t" \
  "s_barrier\n\t"

// half B: store odd step at hso+0x200, then advance one iteration
#define HSTORE_B(WW) \
  "s_mov_b64 exec, %[m0q]\n\t" \
  "ds_write_b32 %[" WW "], v87\n\t" \
  "global_store_dword %[hso], v87, %[hsb] offset:0x200\n\t" \
  "s_mov_b64 exec, -1\n\t" \
  "v_add_u32 %[hso], 0x400, %[hso]\n\t" \
  "s_waitcnt lgkmcnt(0)\n\t" \
  "s_barrier\n\t"

__global__ __launch_bounds__(512)
__attribute__((amdgpu_waves_per_eu(2, 2)))
void k_lstm(const float* __restrict__ g_in, const float* __restrict__ wp,
            float* __restrict__ hs, int T) {
  const int t = threadIdx.x;
  const int j = t & 7;
  const int g8 = t >> 3;
  const int pos = t & 3;               // gate: 0=i 1=f 2=g 3=o
  const int du = (t >> 2) & 1;
  const int unit = 2 * g8 + du;
  const int row = pos * 128 + unit;
  const bool isg = (pos == 2);

  __shared__ __align__(16) float hbuf[2][160];
  __shared__ float lds_cap[20736];     // 82944 B occupancy anchor

  if (t == 0) {
    volatile float* vp = lds_cap;
    vp[0] = 0.f;
  }
  if (t < 160) { hbuf[0][t] = 0.f; hbuf[1][t] = 0.f; }

  // ---- ALL setup BEFORE the preload asm ----
  uint32_t ar0 = (uint32_t)(uintptr_t)&hbuf[0][20 * j];
  uint32_t ar1 = (uint32_t)(uintptr_t)&hbuf[1][20 * j];
  uint32_t w0  = (uint32_t)(uintptr_t)&hbuf[0][20 * (unit >> 4) + (unit & 15)];
  uint32_t w1  = (uint32_t)(uintptr_t)&hbuf[1][20 * (unit >> 4) + (unit & 15)];
  uint32_t gio = (uint32_t)(row * 4);
  uint32_t hso = (uint32_t)(unit * 4);
  float kexp = isg ? -2.8853900817779268f : -1.4426950408889634f;
  float sA   = isg ? 2.f : 1.f;
  float sB   = isg ? -1.f : 0.f;
  unsigned long long m0q  = __ballot(pos == 0);
  unsigned long long modd = __ballot((pos & 1) != 0);
  unsigned long long mb4  = __ballot((t & 4) == 0);   // even banks: need src[i+4]
  float cc = 0.f, ga = 0.f, gb = 0.f;
  int cnt = T >> 1;                     // T is even (20000)
  const float* wr = wp + (size_t)t * 128;

  // -------- one-time weight preload into physical v128..v255 --------
  asm volatile(
    "global_load_dwordx4 v[128:131], %0, off\n\t"
    "global_load_dwordx4 v[132:135], %0, off offset:16\n\t"
    "global_load_dwordx4 v[136:139], %0, off offset:32\n\t"
    "global_load_dwordx4 v[140:143], %0, off offset:48\n\t"
    "global_load_dwordx4 v[144:147], %0, off offset:64\n\t"
    "global_load_dwordx4 v[148:151], %0, off offset:80\n\t"
    "global_load_dwordx4 v[152:155], %0, off offset:96\n\t"
    "global_load_dwordx4 v[156:159], %0, off offset:112\n\t"
    "global_load_dwordx4 v[160:163], %0, off offset:128\n\t"
    "global_load_dwordx4 v[164:167], %0, off offset:144\n\t"
    "global_load_dwordx4 v[168:171], %0, off offset:160\n\t"
    "global_load_dwordx4 v[172:175], %0, off offset:176\n\t"
    "global_load_dwordx4 v[176:179], %0, off offset:192\n\t"
    "global_load_dwordx4 v[180:183], %0, off offset:208\n\t"
    "global_load_dwordx4 v[184:187], %0, off offset:224\n\t"
    "global_load_dwordx4 v[188:191], %0, off offset:240\n\t"
    "global_load_dwordx4 v[192:195], %0, off offset:256\n\t"
    "global_load_dwordx4 v[196:199], %0, off offset:272\n\t"
    "global_load_dwordx4 v[200:203], %0, off offset:288\n\t"
    "global_load_dwordx4 v[204:207], %0, off offset:304\n\t"
    "global_load_dwordx4 v[208:211], %0, off offset:320\n\t"
    "global_load_dwordx4 v[212:215], %0, off offset:336\n\t"
    "global_load_dwordx4 v[216:219], %0, off offset:352\n\t"
    "global_load_dwordx4 v[220:223], %0, off offset:368\n\t"
    "global_load_dwordx4 v[224:227], %0, off offset:384\n\t"
    "global_load_dwordx4 v[228:231], %0, off offset:400\n\t"
    "global_load_dwordx4 v[232:235], %0, off offset:416\n\t"
    "global_load_dwordx4 v[236:239], %0, off offset:432\n\t"
    "global_load_dwordx4 v[240:243], %0, off offset:448\n\t"
    "global_load_dwordx4 v[244:247], %0, off offset:464\n\t"
    "global_load_dwordx4 v[248:251], %0, off offset:480\n\t"
    "global_load_dwordx4 v[252:255], %0, off offset:496\n\t"
    "s_waitcnt vmcnt(0)"
    :: "v"(wr)
    : "v128","v129","v130","v131","v132","v133","v134","v135",
      "v136","v137","v138","v139","v140","v141","v142","v143",
      "v144","v145","v146","v147","v148","v149","v150","v151",
      "v152","v153","v154","v155","v156","v157","v158","v159",
      "v160","v161","v162","v163","v164","v165","v166","v167",
      "v168","v169","v170","v171","v172","v173","v174","v175",
      "v176","v177","v178","v179","v180","v181","v182","v183",
      "v184","v185","v186","v187","v188","v189","v190","v191",
      "v192","v193","v194","v195","v196","v197","v198","v199",
      "v200","v201","v202","v203","v204","v205","v206","v207",
      "v208","v209","v210","v211","v212","v213","v214","v215",
      "v216","v217","v218","v219","v220","v221","v222","v223",
      "v224","v225","v226","v227","v228","v229","v230","v231",
      "v232","v233","v234","v235","v236","v237","v238","v239",
      "v240","v241","v242","v243","v244","v245","v246","v247",
      "v248","v249","v250","v251","v252","v253","v254","v255");

  __syncthreads();

  asm volatile(
    // prologue: load g rows for steps 0,1; advance gio to step 2
    "global_load_dword %[ga], %[gio], %[gin]\n\t"
    "global_load_dword %[gb], %[gio], %[gin] offset:0x800\n\t"
    "v_add_u32 %[gio], 0x1000, %[gio]\n\t"
    "s_waitcnt vmcnt(0)\n\t"
    "Lscan%=:\n\t"
    // ---- half A: even step, read buf0, write buf1, uses ga ----
    DS_READS("ar0")
    FMACORE
    REDUCE_FIXED
    GLOAD_A("ga")
    ACT_CH
    HSTORE_A("w1")
    // ---- half B: odd step, read buf1, write buf0, uses gb ----
    DS_READS("ar1")
    FMACORE
    REDUCE_FIXED
    GLOAD_B("gb")
    ACT_CH
    HSTORE_B("w0")
    // loop control
    "s_sub_u32 %[cnt], %[cnt], 1\n\t"
    "s_cmp_lg_u32 %[cnt], 0\n\t"
    "s_cbranch_scc1 Lscan%=\n\t"
    : [cc]"=&v"(cc), [ga]"=&v"(ga), [gb]"=&v"(gb),
      [gio]"=&v"(gio), [hso]"=&v"(hso), [cnt]"=&s"(cnt)
    : [gin]"s"(g_in), [hsb]"s"(hs),
      [m0q]"s"(m0q), [modd]"s"(modd), [mb4]"s"(mb4),
      [ar0]"v"(ar0), [ar1]"v"(ar1), [w0]"v"(w0), [w1]"v"(w1),
      [kexp]"v"(kexp), [sA]"v"(sA), [sB]"v"(sB),
      "0"(cc), "1"(ga), "2"(gb), "3"(gio), "4"(hso), "5"(cnt)
    : "memory", "scc",
      "v64","v65","v66","v67","v68","v69","v70","v71",
      "v72","v73","v74","v75","v76","v77","v78","v79",
      "v80","v81","v82","v83","v84","v85","v86","v87",
      "v88","v89","v90","v91","v92","v93","v94","v95",
      "v96","v97","v98","v99","v100","v101","v102","v103",
      "v104","v105","v106","v107","v108","v109","v110","v111",
      "v128","v129","v130","v131","v132","v133","v134","v135",
      "v136","v137","v138","v139","v140","v141","v142","v143",
      "v144","v145","v146","v147","v148","v149","v150","v151",
      "v152","v153","v154","v155","v156","v157","v158","v159",
      "v160","v161","v162","v163","v164","v165","v166","v167",
      "v168","v169","v170","v171","v172","v173","v174","v175",
      "v176","v177","v178","v179","v180","v181","v182","v183",
      "v184","v185","v186","v187","v188","v189","v190","v191",
      "v192","v193","v194","v195","v196","v197","v198","v199",
      "v200","v201","v202","v203","v204","v205","v206","v207",
      "v208","v209","v210","v211","v212","v213","v214","v215",
      "v216","v217","v218","v219","v220","v221","v222","v223",
      "v224","v225","v226","v227","v228","v229","v230","v231",
      "v232","v233","v234","v235","v236","v237","v238","v239",
      "v240","v241","v242","v243","v244","v245","v246","v247",
      "v248","v249","v250","v251","v252","v253","v254","v255");
}

// ---------------- host launch ----------------

extern "C" void kernel_launch(void* const* d_in, const int* in_sizes, int n_in,
                              void* d_out, int out_size, void* d_ws, size_t ws_size,
                              hipStream_t stream) {
  const float* x     = (const float*)d_in[0];
  const void* edges  = d_in[1];
  const float* W1    = (const float*)d_in[2];
  const float* b1    = (const float*)d_in[3];
  const float* W2    = (const float*)d_in[4];
  const float* b2    = (const float*)d_in[5];
  const float* W_ih  = (const float*)d_in[6];
  const float* W_hh  = (const float*)d_in[7];
  const float* b_ih  = (const float*)d_in[8];
  const float* b_hh  = (const float*)d_in[9];
  const float* W_lin = (const float*)d_in[10];
  const float* b_lin = (const float*)d_in[11];
  float* out = (float*)d_out;

  const int N = in_sizes[0] / NF;  // 20000
  const int E = in_sizes[1] / 2;   // 640000
  const int OUTF = 64;

  char* base = (char*)d_ws;
  size_t off = 0;
  auto alloc = [&](size_t b) {
    char* p = base + off;
    off += (b + 255) & ~(size_t)255;
    return p;
  };
  float* dinv = (float*)alloc((size_t)N * 4);
  float* W1T  = (float*)alloc(128 * 128 * 4);
  float* W2T  = (float*)alloc(128 * 128 * 4);
  float* wp   = (float*)alloc(512 * 128 * 4);
  float* bsum = (float*)alloc(512 * 4);
  int*   flag = (int*)alloc(256);
  float* bufA = (float*)alloc((size_t)N * NF * 4);
  float* bufB = (float*)alloc((size_t)N * NF * 4);
  float* bufC = (float*)alloc((size_t)N * NF * 4);
  float* g_in = (float*)alloc(((size_t)N + 4) * (size_t)G4 * 4);  // +4 rows slack (prefetch OOB)
  if (off > ws_size) return;

  k_fill<<<(N + 255) / 256, 256, 0, stream>>>(dinv, 1.0f, N);
  k_detect_i64<<<1, 1, 0, stream>>>((const int*)edges, 1024, flag);
  k_count<<<(E + 255) / 256, 256, 0, stream>>>(edges, flag, dinv, E);
  k_rsqrt<<<(N + 255) / 256, 256, 0, stream>>>(dinv, N);
  k_t128<<<128, 128, 0, stream>>>(W1, W1T);
  k_t128<<<128, 128, 0, stream>>>(W2, W2T);
  k_wprep<<<512, 128, 0, stream>>>(W_hh, wp);
  k_add<<<2, 256, 0, stream>>>(b_ih, b_hh, bsum, 512);

  const int mg = (N + 63) / 64;

  gemm_bt<<<dim3(mg, 2), 256, 0, stream>>>(x, W1T, nullptr, bufA, N, NF, NF);
  hipMemsetAsync(bufB, 0, (size_t)N * NF * 4, stream);
  k_aggregate<<<(E + 7) / 8, 256, 0, stream>>>(bufA, edges, flag, dinv, bufB, E);
  k_finish<<<(N * 32 + 255) / 256, 256, 0, stream>>>(bufB, bufA, dinv, b1, N);

  gemm_bt<<<dim3(mg, 2), 256, 0, stream>>>(bufB, W2T, nullptr, bufA, N, NF, NF);
  hipMemsetAsync(bufC, 0, (size_t)N * NF * 4, stream);
  k_aggregate<<<(E + 7) / 8, 256, 0, stream>>>(bufA, edges, flag, dinv, bufC, E);
  k_finish<<<(N * 32 + 255) / 256, 256, 0, stream>>>(bufC, bufA, dinv, b2, N);

  gemm_bt<<<dim3(mg, 8), 256, 0, stream>>>(bufC, W_ih, bsum, g_in, N, G4, NF);

  k_lstm<<<1, 512, 0, stream>>>(g_in, wp, bufB, N);

  gemm_bt<<<dim3(mg, 1), 256, 0, stream>>>(bufB, W_lin, b_lin, out, N, OUTF, NF);
}